// Round 1
// 437.752 us; speedup vs baseline: 1.1216x; 1.1216x over previous
//
#include <hip/hip_runtime.h>

#define N_NODES 100000
#define N_EDGES 400000
#define N_GRAPHS 2048
#define HID 128
#define NLAYER 4
#define TOUT 5
#define EPSV 1e-5f
#define SLOPE 0.2f
#define NB 98   // (N_NODES+1023)/1024
#define GEMM_BLOCKS 782  // (N_NODES+127)/128

typedef float v4f __attribute__((ext_vector_type(4)));
typedef __bf16 v8bf __attribute__((ext_vector_type(8)));

static __device__ __forceinline__ unsigned short f2bf_bits(float f){
  unsigned u = __builtin_bit_cast(unsigned, f);
  unsigned r = u + 0x7fffu + ((u >> 16) & 1u);
  return (unsigned short)(r >> 16);
}
static __device__ __forceinline__ float bfbits2f(unsigned short s){
  unsigned u = ((unsigned)s) << 16;
  return __builtin_bit_cast(float, u);
}
static __device__ __forceinline__ float bflo(unsigned u){
  return __builtin_bit_cast(float, u << 16);
}
static __device__ __forceinline__ float bfhi(unsigned u){
  return __builtin_bit_cast(float, u & 0xffff0000u);
}
static __device__ __forceinline__ float lrelu(float v){
  return v>0.f ? v : SLOPE*v;
}

// Physical bf16 layout (head-aligned pairing):
//   word u (0..63): b=u>>4, r=u&15 -> holds channels (b*32+r [lo], b*32+16+r [hi]).
//   Lane l (words 2l,2l+1) is entirely head l>>3.
//   contraction position for channel k: kp = (k>>5)*32 + (k&15)*2 + ((k>>4)&1).

// merged setup:
//  blocks 0..15      : mebuf direct (wave-per-output, parallel)
//  block  16         : BN fold
//  blocks 17..1040   : w_ext (split hi/lo)
//  blocks 1041..1296 : wswz (single bf16 W)
//  blocks 1297..1687 : zero deg/fill
//  blocks 1688..     : hinit
__global__ void k_setup(const float* __restrict__ gat_edge_w, const float* __restrict__ att_edge,
                        const float* __restrict__ edge_w, const float* __restrict__ edge_b,
                        const float* __restrict__ gat_bias, const float* __restrict__ gamma,
                        const float* __restrict__ beta, const float* __restrict__ mean,
                        const float* __restrict__ var, const float* __restrict__ gat_lin_w,
                        const float* __restrict__ att_src, const float* __restrict__ att_dst,
                        const float* __restrict__ x, const float* __restrict__ nw,
                        const float* __restrict__ nb, unsigned* __restrict__ h16,
                        float* __restrict__ mebuf, float* __restrict__ bnA, float* __restrict__ bnS,
                        unsigned short* __restrict__ whiE, unsigned short* __restrict__ wloE,
                        unsigned short* __restrict__ whi,
                        int* __restrict__ deg, int* __restrict__ fill){
  int bid = blockIdx.x, t = threadIdx.x;
  if(bid < 16){
    // mebuf[o], o = bid*4 + wave; o<48: edge_w row f=o>>4; o>=48: edge_b
    int wv = t>>6, lane = t&63;
    int o = bid*4 + wv;
    int li = (o<48)? (o&15) : (o-48);
    int f = o>>4;
    int l = li>>2, hh = li&3;
    int c = lane&31, kk = lane>>5;
    float at_c = att_edge[l*128 + hh*32 + c];
    float acc = 0.f;
    #pragma unroll 8
    for(int t2=0; t2<64; ++t2){
      int k = kk*64 + t2;
      float wk = (o<48)? edge_w[f*128+k] : edge_b[k];
      acc += wk * gat_edge_w[l*16384 + k*128 + hh*32 + c];
    }
    acc *= at_c;
    acc += __shfl_xor(acc,1); acc += __shfl_xor(acc,2); acc += __shfl_xor(acc,4);
    acc += __shfl_xor(acc,8); acc += __shfl_xor(acc,16); acc += __shfl_xor(acc,32);
    if(lane==0) mebuf[o] = acc;
  } else if(bid == 16){
    for(int i=t; i<NLAYER*HID; i+=256){
      int l_ = i>>7, pos = i&127, lane = pos>>2, j = pos&3;
      int ch = ((lane>>3)<<5) + ((lane&7)<<1) + ((j&1)<<4) + (j>>1);
      int src = l_*128 + ch;
      float A = gamma[src]*rsqrtf(var[src]+EPSV);
      bnA[i] = A;
      bnS[i] = (gat_bias[src]-mean[src])*A + beta[src];
    }
  } else if(bid <= 1040){
    int wave = t>>6, lane = t&63;
    int i = (bid-17)*8 + wave*2 + (lane>>5);   // 0..8191
    int l_ = i>>11, rest = i&2047, kp = rest>>4, col = rest&15;
    int sub = lane&31;
    float val = 0.f;
    if(col < 8){
      int h_ = col&3, isdst = col>>2;
      int ch = ((kp>>5)<<5) + ((kp&1)<<4) + ((kp&31)>>1);
      const float* at = (isdst? att_dst : att_src);
      val = gat_lin_w[l_*16384 + ch*128 + h_*32 + sub] * at[l_*128 + h_*32 + sub];
    }
    val += __shfl_xor(val,1); val += __shfl_xor(val,2); val += __shfl_xor(val,4);
    val += __shfl_xor(val,8); val += __shfl_xor(val,16);
    if(sub == 0){
      unsigned short hi = f2bf_bits(val);
      unsigned short lo = f2bf_bits(val - bfbits2f(hi));
      int kb=kp>>5, quad=(kp>>3)&3, jj=kp&7, lane2=quad*16+col;
      int dst = ((l_*4+kb)*64 + lane2)*8 + jj;
      whiE[dst]=hi; wloE[dst]=lo;
    }
  } else if(bid <= 1296){
    int tg = (bid-1041)*256 + t;              // 0..65535 == dst index
    int base = tg>>9, off = tg&511;
    int l = base>>5, kb=(base>>3)&3, cg=base&7;
    int lane = off>>3, j = off&7;
    int quad = lane>>4, r = lane&15;
    int kp = kb*32 + quad*8 + j;
    int k = ((kp>>5)<<5) | ((kp&1)<<4) | ((kp&31)>>1);
    whi[tg] = f2bf_bits(gat_lin_w[l*16384 + k*128 + cg*16 + r]);
  } else if(bid <= 1687){
    int tg = (bid-1297)*256 + t;
    if(tg < N_NODES){ deg[tg]=0; fill[tg]=0; }
  } else {
    int node = (bid-1688)*4 + (t>>6);
    int c = t&63;
    int ch = ((c>>4)<<5) + (c&15);
    float a0 = nb[ch], a1 = nb[ch+16];
    #pragma unroll
    for(int f=0; f<7; ++f){
      float xv = x[node*7+f];
      a0 += xv*nw[f*HID+ch];
      a1 += xv*nw[f*HID+ch+16];
    }
    unsigned p = (unsigned)f2bf_bits(a0) | ((unsigned)f2bf_bits(a1)<<16);
    h16[(size_t)node*64 + c] = p;
  }
}

// deg count only (after zeroing in k_setup)
__global__ void k_deg(const int* __restrict__ ei, int* __restrict__ deg){
  int e = blockIdx.x*256 + threadIdx.x;
  if(e < N_EDGES) atomicAdd(&deg[ei[N_EDGES+e]], 1);
}

// scan phase 1: per-chunk sums
__global__ void k_scan1(const int* __restrict__ deg, int* __restrict__ part){
  __shared__ int s[256];
  int t=threadIdx.x; int base = blockIdx.x*1024 + t*4;
  int sum=0;
  #pragma unroll
  for(int j=0;j<4;++j){ int i=base+j; sum += (i<N_NODES)? deg[i]:0; }
  s[t]=sum; __syncthreads();
  for(int off=128; off>0; off>>=1){ if(t<off) s[t]+=s[t+off]; __syncthreads(); }
  if(t==0) part[blockIdx.x]=s[0];
}
// scan phase 2+3 fused
__global__ void k_scan3(const int* __restrict__ deg, const int* __restrict__ part,
                        int* __restrict__ rowptr){
  __shared__ int s[256];
  int t=threadIdx.x, b=blockIdx.x;
  int g = 0, tot = 0;
  for(int i=0;i<NB;++i){ int v = part[i]; g += (i<b)? v : 0; tot += v; }
  if(b==0 && t==0) rowptr[N_NODES]=tot;
  int base = b*1024 + t*4;
  int v[4]; int sum=0; int pre[4];
  #pragma unroll
  for(int j=0;j<4;++j){ int i=base+j; v[j]=(i<N_NODES)?deg[i]:0; pre[j]=sum; sum+=v[j]; }
  s[t]=sum; __syncthreads();
  for(int off=1; off<256; off<<=1){
    int xv = (t>=off)? s[t-off]:0; __syncthreads();
    s[t]+=xv; __syncthreads();
  }
  int toff = (t>0)? s[t-1]:0;
  #pragma unroll
  for(int j=0;j<4;++j){ int i=base+j; if(i<N_NODES) rowptr[i]=g+toff+pre[j]; }
}

// xh = h16 @ W[l], 2 row-tiles per wave; as_/ad_ via split-precision w_ext tile.
// LDS-staged coalesced stores. Layer-0 launch carries extra blocks that build
// the CSR (fill) — uniform per-block branch, no data conflicts.
__global__ void k_gemm(const unsigned short* __restrict__ h16,
                       const unsigned short* __restrict__ whi,
                       const unsigned short* __restrict__ whiE,
                       const unsigned short* __restrict__ wloE,
                       unsigned* __restrict__ xhb, float* __restrict__ as_, float* __restrict__ ad_,
                       const int* __restrict__ ei, const float* __restrict__ ea,
                       const int* __restrict__ rowptr, int* __restrict__ fill,
                       int* __restrict__ csr_src, float* __restrict__ ea_csr){
  if(blockIdx.x >= GEMM_BLOCKS){
    int e = (blockIdx.x - GEMM_BLOCKS)*256 + threadIdx.x;
    if(e < N_EDGES){
      int dst = ei[N_EDGES+e];
      int pos = rowptr[dst] + atomicAdd(&fill[dst],1);
      csr_src[pos] = ei[e];
      v4f q = {ea[e*3], ea[e*3+1], ea[e*3+2], 0.f};
      ((v4f*)ea_csr)[pos] = q;
    }
    return;
  }
  __shared__ unsigned sxh[4][2][16*68];
  int wave = threadIdx.x>>6, lane = threadIdx.x&63;
  int base = blockIdx.x*128;
  int q = lane>>4, r = lane&15;
  int r0[2];
  r0[0] = base + wave*16;
  r0[1] = base + 64 + wave*16;
  if(r0[0] > N_NODES-16) r0[0] = N_NODES-16;
  if(r0[1] > N_NODES-16) r0[1] = N_NODES-16;
  v8bf av[2][4];
  #pragma unroll
  for(int tt=0;tt<2;++tt){
    const unsigned short* hrow = h16 + (size_t)(r0[tt] + r)*HID;
    #pragma unroll
    for(int kb=0;kb<4;++kb)
      av[tt][kb] = *(const v8bf*)(hrow + kb*32 + q*8);
  }
  v4f acc[2][8];
  #pragma unroll
  for(int cg=0;cg<8;++cg){
    v4f a0 = {0.f,0.f,0.f,0.f}, a1 = {0.f,0.f,0.f,0.f};
    #pragma unroll
    for(int kb=0;kb<4;++kb){
      v8bf bhi = *(const v8bf*)(whi + ((kb*8+cg)*64 + lane)*8);
      a0 = __builtin_amdgcn_mfma_f32_16x16x32_bf16(av[0][kb], bhi, a0, 0,0,0);
      a1 = __builtin_amdgcn_mfma_f32_16x16x32_bf16(av[1][kb], bhi, a1, 0,0,0);
    }
    acc[0][cg]=a0; acc[1][cg]=a1;
  }
  v4f acc8[2] = {{0.f,0.f,0.f,0.f},{0.f,0.f,0.f,0.f}};
  #pragma unroll
  for(int kb=0;kb<4;++kb){
    v8bf bhi = *(const v8bf*)(whiE + (kb*64 + lane)*8);
    v8bf blo = *(const v8bf*)(wloE + (kb*64 + lane)*8);
    #pragma unroll
    for(int tt=0;tt<2;++tt){
      acc8[tt] = __builtin_amdgcn_mfma_f32_16x16x32_bf16(av[tt][kb], blo, acc8[tt], 0,0,0);
      acc8[tt] = __builtin_amdgcn_mfma_f32_16x16x32_bf16(av[tt][kb], bhi, acc8[tt], 0,0,0);
    }
  }
  #pragma unroll
  for(int tt=0;tt<2;++tt){
    #pragma unroll
    for(int m=0;m<4;++m){
      #pragma unroll
      for(int reg=0;reg<4;++reg){
        unsigned pack = (unsigned)f2bf_bits(acc[tt][2*m][reg]) | ((unsigned)f2bf_bits(acc[tt][2*m+1][reg])<<16);
        sxh[wave][tt][(q*4+reg)*68 + m*16 + r] = pack;
      }
    }
  }
  __syncthreads();
  {
    int rr = lane>>4, c4 = lane&15;
    #pragma unroll
    for(int tt=0;tt<2;++tt){
      #pragma unroll
      for(int rg=0; rg<4; ++rg){
        int i = rg*4 + rr;
        uint4 v = *(const uint4*)&sxh[wave][tt][i*68 + c4*4];
        *(uint4*)(xhb + (size_t)(r0[tt] + i)*64 + c4*4) = v;
      }
    }
  }
  #pragma unroll
  for(int tt=0;tt<2;++tt){
    if(r < 4){
      #pragma unroll
      for(int reg=0;reg<4;++reg)
        as_[(size_t)(r0[tt] + q*4 + reg)*4 + r] = acc8[tt][reg];
    } else if(r < 8){
      #pragma unroll
      for(int reg=0;reg<4;++reg)
        ad_[(size_t)(r0[tt] + q*4 + reg)*4 + (r-4)] = acc8[tt][reg];
    }
  }
}

// half-wave (32 lanes) per node, 8 nodes/block. Phase A: parallel softmax
// anchored at self-logit; deg<=8 single-round fast path (97.9% of nodes at
// Poisson(4)), deg<=16 two-round path, serial online-softmax for deg>16.
// All shuffle reductions use xor masks 4/8/16 (stay within the half-wave).
// Phase B: per-iter each lane gathers 2 rows for its node (wave instruction
// still covers 2 rows — one per half — same VMEM density as before).
// Epilogue: all 32 lanes active (was: half the wave idle).
__global__ void k_aggr(const unsigned* __restrict__ xhb, const float* __restrict__ as_,
    const float* __restrict__ ad_, const float* __restrict__ ea_csr,
    const float* __restrict__ mebuf,
    const int* __restrict__ rowptr, const int* __restrict__ csr_src,
    const float* __restrict__ bnA_l, const float* __restrict__ bnS_l,
    unsigned* __restrict__ h16, int layer){
  __shared__ float lds_coef[8][16*4];
  __shared__ int   lds_src[8][16];
  int hw = threadIdx.x>>5, lh = threadIdx.x&31;
  int lane = threadIdx.x&63;
  int node = blockIdx.x*8 + hw;
  if(node >= N_NODES) return;
  int s = rowptr[node], e = rowptr[node+1];
  int deg = e - s;
  int hh2 = lh>>3;
  const uint2* xrow = (const uint2*)xhb;
  float a0,a1,a2,a3;

  if(deg <= 16){
    int eidx = lh>>2, h = lh&3;
    int li = layer*4+h;
    float mec0=mebuf[li], mec1=mebuf[16+li], mec2=mebuf[32+li], meb=mebuf[48+li];
    float ad_h = ad_[node*4+h];
    int j0 = eidx;
    float t0 = 0.f, g0 = 0.f;
    int s0 = node;
    bool v0 = (j0 < deg);
    if(v0){
      s0 = csr_src[s+j0];
      v4f qq = ((const v4f*)ea_csr)[s+j0];
      t0 = qq.x*mec0 + qq.y*mec1 + qq.z*mec2;
      g0 = lrelu(as_[s0*4+h] + ad_h + t0 + meb);
    }
    float ts, ds, inv;
    if(deg <= 8){
      ts = t0;
      ts += __shfl_xor(ts,4); ts += __shfl_xor(ts,8); ts += __shfl_xor(ts,16);
      float lt = (deg>0) ? ts/(float)deg + meb : 0.f;
      float al = lrelu(as_[node*4+h] + ad_h + lt);
      float e0 = v0 ? __expf(g0-al) : 0.f;
      ds = e0;
      ds += __shfl_xor(ds,4); ds += __shfl_xor(ds,8); ds += __shfl_xor(ds,16);
      inv = 1.f/(ds+1.f);
      if(h==0) lds_src[hw][j0] = s0;
      lds_coef[hw][j0*4+h] = e0*inv;
    } else {
      int j1 = 8+eidx;
      float t1 = 0.f, g1 = 0.f;
      int s1 = node;
      bool v1 = (j1 < deg);
      if(v1){
        s1 = csr_src[s+j1];
        v4f qq = ((const v4f*)ea_csr)[s+j1];
        t1 = qq.x*mec0 + qq.y*mec1 + qq.z*mec2;
        g1 = lrelu(as_[s1*4+h] + ad_h + t1 + meb);
      }
      ts = t0+t1;
      ts += __shfl_xor(ts,4); ts += __shfl_xor(ts,8); ts += __shfl_xor(ts,16);
      float lt = ts/(float)deg + meb;
      float al = lrelu(as_[node*4+h] + ad_h + lt);
      float e0 = v0 ? __expf(g0-al) : 0.f;
      float e1 = v1 ? __expf(g1-al) : 0.f;
      ds = e0+e1;
      ds += __shfl_xor(ds,4); ds += __shfl_xor(ds,8); ds += __shfl_xor(ds,16);
      inv = 1.f/(ds+1.f);
      if(h==0){ lds_src[hw][j0]=s0; lds_src[hw][j1]=s1; }
      lds_coef[hw][j0*4+h] = e0*inv;
      lds_coef[hw][j1*4+h] = e1*inv;
    }
    // ---- phase B ----
    float cs4 = __shfl(inv, (lane&32) | hh2);
    uint2 su = xrow[(size_t)node*32 + lh];
    int pdeg = (deg+1)&~1;
    a0=a1=a2=a3=0.f;
    for(int j=0;j<pdeg;j+=2){
      float ca = lds_coef[hw][j*4+hh2];
      float cb = lds_coef[hw][(j+1)*4+hh2];
      int sa = lds_src[hw][j], sb = lds_src[hw][j+1];
      uint2 ua = xrow[(size_t)sa*32+lh];
      uint2 ub = xrow[(size_t)sb*32+lh];
      a0 += ca*bflo(ua.x) + cb*bflo(ub.x);
      a1 += ca*bfhi(ua.x) + cb*bfhi(ub.x);
      a2 += ca*bflo(ua.y) + cb*bflo(ub.y);
      a3 += ca*bfhi(ua.y) + cb*bfhi(ub.y);
    }
    a0 += cs4*bflo(su.x); a1 += cs4*bfhi(su.x);
    a2 += cs4*bflo(su.y); a3 += cs4*bfhi(su.y);
  } else {
    // serial online-softmax path, runs on the half-wave's 32 lanes
    int li = layer*4+hh2;
    float mec0=mebuf[li], mec1=mebuf[16+li], mec2=mebuf[32+li], meb=mebuf[48+li];
    float adv = ad_[node*4+hh2];
    float ts = 0.f;
    for(int j=s;j<e;++j){
      v4f qq = ((const v4f*)ea_csr)[j];
      ts += qq.x*mec0 + qq.y*mec1 + qq.z*mec2;
    }
    float al = lrelu(as_[node*4+hh2] + adv + ts/(float)deg + meb);
    float m = al, d = 1.f;
    uint2 su = xrow[(size_t)node*32 + lh];
    float c0=bflo(su.x),c1=bfhi(su.x),c2=bflo(su.y),c3=bfhi(su.y);
    for(int j=s;j<e;++j){
      int sr = csr_src[j];
      v4f qq = ((const v4f*)ea_csr)[j];
      float b = lrelu(as_[sr*4+hh2] + adv + qq.x*mec0+qq.y*mec1+qq.z*mec2+meb);
      uint2 uv = xrow[(size_t)sr*32 + lh];
      float nm = fmaxf(m,b);
      float sc = __expf(m-nm), eb = __expf(b-nm);
      d = d*sc + eb;
      c0 = c0*sc + eb*bflo(uv.x); c1 = c1*sc + eb*bfhi(uv.x);
      c2 = c2*sc + eb*bflo(uv.y); c3 = c3*sc + eb*bfhi(uv.y);
      m = nm;
    }
    float inv2 = 1.f/d;
    a0=c0*inv2; a1=c1*inv2; a2=c2*inv2; a3=c3*inv2;
  }

  // epilogue: permuted folded BN + relu + bf16 residual; all 32 lanes active
  {
    const v4f* A4 = (const v4f*)bnA_l;
    const v4f* S4 = (const v4f*)bnS_l;
    v4f A = A4[lh], S = S4[lh];
    uint2 hr = ((const uint2*)h16)[(size_t)node*32 + lh];
    float o0 = fmaxf(a0*A.x+S.x, 0.f) + bflo(hr.x);
    float o1 = fmaxf(a1*A.y+S.y, 0.f) + bfhi(hr.x);
    float o2 = fmaxf(a2*A.z+S.z, 0.f) + bflo(hr.y);
    float o3 = fmaxf(a3*A.w+S.w, 0.f) + bfhi(hr.y);
    uint2 p;
    p.x = (unsigned)f2bf_bits(o0) | ((unsigned)f2bf_bits(o1)<<16);
    p.y = (unsigned)f2bf_bits(o2) | ((unsigned)f2bf_bits(o3)<<16);
    ((uint2*)h16)[(size_t)node*32 + lh] = p;
  }
}

// fused pool + head
__global__ void k_tail(const unsigned* __restrict__ h16, const int* __restrict__ batch,
   const float* __restrict__ gf,
   const float* __restrict__ gc_w, const float* __restrict__ gc_b,
   const float* __restrict__ gf1_w, const float* __restrict__ gf1_b,
   const float* __restrict__ gf2_w, const float* __restrict__ gf2_b,
   const float* __restrict__ p1_w, const float* __restrict__ p1_b,
   const float* __restrict__ p2_w, const float* __restrict__ p2_b,
   const float* __restrict__ p3_w, const float* __restrict__ p3_b,
   float* __restrict__ out){
  __shared__ float sg[384];
  __shared__ int sb[2];
  __shared__ float comb[192];
  __shared__ float hid1[64];
  __shared__ float r1[128];
  __shared__ float r2[64];
  int g = blockIdx.x, t = threadIdx.x;
  if(t < 2){
    int target = g + t;
    int lo=0, hi=N_NODES;
    while(lo<hi){ int mid=(lo+hi)>>1; if(batch[mid] < target) lo=mid+1; else hi=mid; }
    sb[t]=lo;
  }
  __syncthreads();
  {
    int s = sb[0], e = sb[1];
    int u = ((t>>5)<<4) + (t&15);
    int hiflag = (t>>4)&1;
    float sum=0.f, mx=-3.4e38f;
    for(int i=s;i<e;++i){
      unsigned uv = h16[(size_t)i*64 + u];
      float v = hiflag ? bfhi(uv) : bflo(uv);
      sum+=v; mx=fmaxf(mx,v);
    }
    int cnt = e-s;
    float meanv = sum / (float)(cnt>1?cnt:1);
    if(cnt==0) mx=0.f;
    sg[t] = meanv;
    sg[128+t] = mx;
    sg[256+t] = sum;
  }
  if(t<64){
    float a = gf1_b[t];
    #pragma unroll
    for(int i=0;i<10;++i) a += gf[g*10+i]*gf1_w[i*64+t];
    hid1[t] = fmaxf(a,0.f);
  }
  __syncthreads();
  if(t<64){
    float a = gf2_b[t];
    for(int k=0;k<64;++k) a += hid1[k]*gf2_w[k*64+t];
    comb[128+t] = a;
  }
  {
    float a = gc_b[t];
    for(int k=0;k<384;++k) a += sg[k]*gc_w[k*128+t];
    comb[t] = fmaxf(a,0.f);
  }
  __syncthreads();
  {
    float a = p1_b[t];
    for(int k=0;k<192;++k) a += comb[k]*p1_w[k*128+t];
    r1[t] = fmaxf(a,0.f);
  }
  __syncthreads();
  if(t<64){
    float a = p2_b[t];
    for(int k=0;k<128;++k) a += r1[k]*p2_w[k*64+t];
    r2[t] = fmaxf(a,0.f);
  }
  __syncthreads();
  if(t<TOUT){
    float a = p3_b[t];
    for(int k=0;k<64;++k) a += r2[k]*p3_w[k*TOUT+t];
    out[g*TOUT+t] = a;
  }
}

extern "C" void kernel_launch(void* const* d_in, const int* in_sizes, int n_in,
                              void* d_out, int out_size, void* d_ws, size_t ws_size,
                              hipStream_t stream){
  (void)in_sizes; (void)n_in; (void)out_size; (void)ws_size;
  const float* x        = (const float*)d_in[0];
  const int*   ei       = (const int*)d_in[1];
  const float* ea       = (const float*)d_in[2];
  const int*   batch    = (const int*)d_in[3];
  const float* gfin     = (const float*)d_in[4];
  const float* node_w   = (const float*)d_in[5];
  const float* node_b   = (const float*)d_in[6];
  const float* edge_w   = (const float*)d_in[7];
  const float* edge_b   = (const float*)d_in[8];
  const float* gat_lin_w  = (const float*)d_in[9];
  const float* gat_edge_w = (const float*)d_in[10];
  const float* att_src  = (const float*)d_in[11];
  const float* att_dst  = (const float*)d_in[12];
  const float* att_edge = (const float*)d_in[13];
  const float* gat_bias = (const float*)d_in[14];
  const float* bn_gamma = (const float*)d_in[15];
  const float* bn_beta  = (const float*)d_in[16];
  const float* bn_mean  = (const float*)d_in[17];
  const float* bn_var   = (const float*)d_in[18];
  const float* gc_w = (const float*)d_in[19];
  const float* gc_b = (const float*)d_in[20];
  const float* gf1_w = (const float*)d_in[21];
  const float* gf1_b = (const float*)d_in[22];
  const float* gf2_w = (const float*)d_in[23];
  const float* gf2_b = (const float*)d_in[24];
  const float* p1_w = (const float*)d_in[25];
  const float* p1_b = (const float*)d_in[26];
  const float* p2_w = (const float*)d_in[27];
  const float* p2_b = (const float*)d_in[28];
  const float* p3_w = (const float*)d_in[29];
  const float* p3_b = (const float*)d_in[30];
  float* out = (float*)d_out;

  char* w = (char*)d_ws;
  size_t o = 0;
  auto carve = [&](size_t bytes)->char*{
    char* p = w + o; o += (bytes + 255) & ~(size_t)255; return p;
  };
  unsigned* xhb = (unsigned*)carve((size_t)N_NODES*64*4);
  unsigned* h16 = (unsigned*)carve((size_t)N_NODES*64*4);
  float* ea_csr = (float*)carve((size_t)N_EDGES*4*4);
  float* as_    = (float*)carve((size_t)N_NODES*4*4);
  float* ad_    = (float*)carve((size_t)N_NODES*4*4);
  int* deg      = (int*)carve((size_t)N_NODES*4);
  int* rowptr   = (int*)carve((size_t)(N_NODES+1)*4);
  int* fill     = (int*)carve((size_t)N_NODES*4);
  int* csr_src  = (int*)carve((size_t)N_EDGES*4);
  int* part     = (int*)carve(1024*4);
  float* mebuf  = (float*)carve(64*4);
  float* bnA    = (float*)carve((size_t)NLAYER*HID*4);
  float* bnS    = (float*)carve((size_t)NLAYER*HID*4);
  unsigned short* whi = (unsigned short*)carve(65536*2);
  unsigned short* whiE = (unsigned short*)carve(8192*2);
  unsigned short* wloE = (unsigned short*)carve(8192*2);

  // setup: mebuf + BNfold + w_ext + wswz + zero(deg,fill) + hinit
  k_setup<<<1688 + N_NODES/4, 256, 0, stream>>>(gat_edge_w, att_edge, edge_w, edge_b,
        gat_bias, bn_gamma, bn_beta, bn_mean, bn_var,
        gat_lin_w, att_src, att_dst, x, node_w, node_b, h16,
        mebuf, bnA, bnS, whiE, wloE, whi, deg, fill);
  k_deg<<<(N_EDGES+255)/256, 256, 0, stream>>>(ei, deg);
  k_scan1<<<NB,256,0,stream>>>(deg, part);
  k_scan3<<<NB,256,0,stream>>>(deg, part, rowptr);

  for(int l=0;l<NLAYER;++l){
    int gb = (l==0) ? GEMM_BLOCKS + (N_EDGES+255)/256 : GEMM_BLOCKS;
    k_gemm<<<gb,256,0,stream>>>((const unsigned short*)h16,
        whi + l*16384, whiE + l*2048, wloE + l*2048,
        xhb, as_, ad_, ei, ea, rowptr, fill, csr_src, ea_csr);
    k_aggr<<<(N_NODES+7)/8,256,0,stream>>>(xhb, as_, ad_, ea_csr, mebuf,
        rowptr, csr_src, bnA + l*128, bnS + l*128, h16, l);
  }

  k_tail<<<N_GRAPHS,128,0,stream>>>(h16, batch, gfin, gc_w, gc_b, gf1_w, gf1_b,
        gf2_w, gf2_b, p1_w, p1_b, p2_w, p2_b, p3_w, p3_b, out);
}

// Round 2
// 432.816 us; speedup vs baseline: 1.1344x; 1.0114x over previous
//
#include <hip/hip_runtime.h>

#define N_NODES 100000
#define N_EDGES 400000
#define N_GRAPHS 2048
#define HID 128
#define NLAYER 4
#define TOUT 5
#define EPSV 1e-5f
#define SLOPE 0.2f
#define NB 98   // (N_NODES+1023)/1024
#define GEMM_BLOCKS 782  // (N_NODES+127)/128

typedef float v4f __attribute__((ext_vector_type(4)));
typedef __bf16 v8bf __attribute__((ext_vector_type(8)));

static __device__ __forceinline__ unsigned short f2bf_bits(float f){
  unsigned u = __builtin_bit_cast(unsigned, f);
  unsigned r = u + 0x7fffu + ((u >> 16) & 1u);
  return (unsigned short)(r >> 16);
}
static __device__ __forceinline__ float bfbits2f(unsigned short s){
  unsigned u = ((unsigned)s) << 16;
  return __builtin_bit_cast(float, u);
}
static __device__ __forceinline__ float bflo(unsigned u){
  return __builtin_bit_cast(float, u << 16);
}
static __device__ __forceinline__ float bfhi(unsigned u){
  return __builtin_bit_cast(float, u & 0xffff0000u);
}
static __device__ __forceinline__ float lrelu(float v){
  return v>0.f ? v : SLOPE*v;
}

// Physical bf16 layout (head-aligned pairing):
//   word u (0..63): b=u>>4, r=u&15 -> holds channels (b*32+r [lo], b*32+16+r [hi]).
//   Lane l (words 2l,2l+1) is entirely head l>>3.
//   contraction position for channel k: kp = (k>>5)*32 + (k&15)*2 + ((k>>4)&1).

// merged setup:
//  blocks 0..15      : mebuf direct (wave-per-output, parallel)
//  block  16         : BN fold
//  blocks 17..1040   : w_ext (split hi/lo)
//  blocks 1041..1296 : wswz (single bf16 W)
//  blocks 1297..1687 : zero deg/fill
//  blocks 1688..     : hinit
__global__ void k_setup(const float* __restrict__ gat_edge_w, const float* __restrict__ att_edge,
                        const float* __restrict__ edge_w, const float* __restrict__ edge_b,
                        const float* __restrict__ gat_bias, const float* __restrict__ gamma,
                        const float* __restrict__ beta, const float* __restrict__ mean,
                        const float* __restrict__ var, const float* __restrict__ gat_lin_w,
                        const float* __restrict__ att_src, const float* __restrict__ att_dst,
                        const float* __restrict__ x, const float* __restrict__ nw,
                        const float* __restrict__ nb, unsigned* __restrict__ h16,
                        float* __restrict__ mebuf, float* __restrict__ bnA, float* __restrict__ bnS,
                        unsigned short* __restrict__ whiE, unsigned short* __restrict__ wloE,
                        unsigned short* __restrict__ whi,
                        int* __restrict__ deg, int* __restrict__ fill){
  int bid = blockIdx.x, t = threadIdx.x;
  if(bid < 16){
    // mebuf[o], o = bid*4 + wave; o<48: edge_w row f=o>>4; o>=48: edge_b
    int wv = t>>6, lane = t&63;
    int o = bid*4 + wv;
    int li = (o<48)? (o&15) : (o-48);
    int f = o>>4;
    int l = li>>2, hh = li&3;
    int c = lane&31, kk = lane>>5;
    float at_c = att_edge[l*128 + hh*32 + c];
    float acc = 0.f;
    #pragma unroll 8
    for(int t2=0; t2<64; ++t2){
      int k = kk*64 + t2;
      float wk = (o<48)? edge_w[f*128+k] : edge_b[k];
      acc += wk * gat_edge_w[l*16384 + k*128 + hh*32 + c];
    }
    acc *= at_c;
    acc += __shfl_xor(acc,1); acc += __shfl_xor(acc,2); acc += __shfl_xor(acc,4);
    acc += __shfl_xor(acc,8); acc += __shfl_xor(acc,16); acc += __shfl_xor(acc,32);
    if(lane==0) mebuf[o] = acc;
  } else if(bid == 16){
    for(int i=t; i<NLAYER*HID; i+=256){
      int l_ = i>>7, pos = i&127, lane = pos>>2, j = pos&3;
      int ch = ((lane>>3)<<5) + ((lane&7)<<1) + ((j&1)<<4) + (j>>1);
      int src = l_*128 + ch;
      float A = gamma[src]*rsqrtf(var[src]+EPSV);
      bnA[i] = A;
      bnS[i] = (gat_bias[src]-mean[src])*A + beta[src];
    }
  } else if(bid <= 1040){
    int wave = t>>6, lane = t&63;
    int i = (bid-17)*8 + wave*2 + (lane>>5);   // 0..8191
    int l_ = i>>11, rest = i&2047, kp = rest>>4, col = rest&15;
    int sub = lane&31;
    float val = 0.f;
    if(col < 8){
      int h_ = col&3, isdst = col>>2;
      int ch = ((kp>>5)<<5) + ((kp&1)<<4) + ((kp&31)>>1);
      const float* at = (isdst? att_dst : att_src);
      val = gat_lin_w[l_*16384 + ch*128 + h_*32 + sub] * at[l_*128 + h_*32 + sub];
    }
    val += __shfl_xor(val,1); val += __shfl_xor(val,2); val += __shfl_xor(val,4);
    val += __shfl_xor(val,8); val += __shfl_xor(val,16);
    if(sub == 0){
      unsigned short hi = f2bf_bits(val);
      unsigned short lo = f2bf_bits(val - bfbits2f(hi));
      int kb=kp>>5, quad=(kp>>3)&3, jj=kp&7, lane2=quad*16+col;
      int dst = ((l_*4+kb)*64 + lane2)*8 + jj;
      whiE[dst]=hi; wloE[dst]=lo;
    }
  } else if(bid <= 1296){
    int tg = (bid-1041)*256 + t;              // 0..65535 == dst index
    int base = tg>>9, off = tg&511;
    int l = base>>5, kb=(base>>3)&3, cg=base&7;
    int lane = off>>3, j = off&7;
    int quad = lane>>4, r = lane&15;
    int kp = kb*32 + quad*8 + j;
    int k = ((kp>>5)<<5) | ((kp&1)<<4) | ((kp&31)>>1);
    whi[tg] = f2bf_bits(gat_lin_w[l*16384 + k*128 + cg*16 + r]);
  } else if(bid <= 1687){
    int tg = (bid-1297)*256 + t;
    if(tg < N_NODES){ deg[tg]=0; fill[tg]=0; }
  } else {
    int node = (bid-1688)*4 + (t>>6);
    int c = t&63;
    int ch = ((c>>4)<<5) + (c&15);
    float a0 = nb[ch], a1 = nb[ch+16];
    #pragma unroll
    for(int f=0; f<7; ++f){
      float xv = x[node*7+f];
      a0 += xv*nw[f*HID+ch];
      a1 += xv*nw[f*HID+ch+16];
    }
    unsigned p = (unsigned)f2bf_bits(a0) | ((unsigned)f2bf_bits(a1)<<16);
    h16[(size_t)node*64 + c] = p;
  }
}

// deg count only (after zeroing in k_setup)
__global__ void k_deg(const int* __restrict__ ei, int* __restrict__ deg){
  int e = blockIdx.x*256 + threadIdx.x;
  if(e < N_EDGES) atomicAdd(&deg[ei[N_EDGES+e]], 1);
}

// scan phase 1: per-chunk sums
__global__ void k_scan1(const int* __restrict__ deg, int* __restrict__ part){
  __shared__ int s[256];
  int t=threadIdx.x; int base = blockIdx.x*1024 + t*4;
  int sum=0;
  #pragma unroll
  for(int j=0;j<4;++j){ int i=base+j; sum += (i<N_NODES)? deg[i]:0; }
  s[t]=sum; __syncthreads();
  for(int off=128; off>0; off>>=1){ if(t<off) s[t]+=s[t+off]; __syncthreads(); }
  if(t==0) part[blockIdx.x]=s[0];
}
// scan phase 2+3 fused
__global__ void k_scan3(const int* __restrict__ deg, const int* __restrict__ part,
                        int* __restrict__ rowptr){
  __shared__ int s[256];
  int t=threadIdx.x, b=blockIdx.x;
  int g = 0, tot = 0;
  for(int i=0;i<NB;++i){ int v = part[i]; g += (i<b)? v : 0; tot += v; }
  if(b==0 && t==0) rowptr[N_NODES]=tot;
  int base = b*1024 + t*4;
  int v[4]; int sum=0; int pre[4];
  #pragma unroll
  for(int j=0;j<4;++j){ int i=base+j; v[j]=(i<N_NODES)?deg[i]:0; pre[j]=sum; sum+=v[j]; }
  s[t]=sum; __syncthreads();
  for(int off=1; off<256; off<<=1){
    int xv = (t>=off)? s[t-off]:0; __syncthreads();
    s[t]+=xv; __syncthreads();
  }
  int toff = (t>0)? s[t-1]:0;
  #pragma unroll
  for(int j=0;j<4;++j){ int i=base+j; if(i<N_NODES) rowptr[i]=g+toff+pre[j]; }
}

// xh = h16 @ W[l], 2 row-tiles per wave; as_/ad_ via split-precision w_ext tile.
// LDS-staged coalesced stores. Layer-0 launch carries extra blocks that build
// the CSR (fill) — uniform per-block branch, no data conflicts.
__global__ void k_gemm(const unsigned short* __restrict__ h16,
                       const unsigned short* __restrict__ whi,
                       const unsigned short* __restrict__ whiE,
                       const unsigned short* __restrict__ wloE,
                       unsigned* __restrict__ xhb, float* __restrict__ as_, float* __restrict__ ad_,
                       const int* __restrict__ ei, const float* __restrict__ ea,
                       const int* __restrict__ rowptr, int* __restrict__ fill,
                       int* __restrict__ csr_src, float* __restrict__ ea_csr){
  if(blockIdx.x >= GEMM_BLOCKS){
    int e = (blockIdx.x - GEMM_BLOCKS)*256 + threadIdx.x;
    if(e < N_EDGES){
      int dst = ei[N_EDGES+e];
      int pos = rowptr[dst] + atomicAdd(&fill[dst],1);
      csr_src[pos] = ei[e];
      v4f q = {ea[e*3], ea[e*3+1], ea[e*3+2], 0.f};
      ((v4f*)ea_csr)[pos] = q;
    }
    return;
  }
  __shared__ unsigned sxh[4][2][16*68];
  int wave = threadIdx.x>>6, lane = threadIdx.x&63;
  int base = blockIdx.x*128;
  int q = lane>>4, r = lane&15;
  int r0[2];
  r0[0] = base + wave*16;
  r0[1] = base + 64 + wave*16;
  if(r0[0] > N_NODES-16) r0[0] = N_NODES-16;
  if(r0[1] > N_NODES-16) r0[1] = N_NODES-16;
  v8bf av[2][4];
  #pragma unroll
  for(int tt=0;tt<2;++tt){
    const unsigned short* hrow = h16 + (size_t)(r0[tt] + r)*HID;
    #pragma unroll
    for(int kb=0;kb<4;++kb)
      av[tt][kb] = *(const v8bf*)(hrow + kb*32 + q*8);
  }
  v4f acc[2][8];
  #pragma unroll
  for(int cg=0;cg<8;++cg){
    v4f a0 = {0.f,0.f,0.f,0.f}, a1 = {0.f,0.f,0.f,0.f};
    #pragma unroll
    for(int kb=0;kb<4;++kb){
      v8bf bhi = *(const v8bf*)(whi + ((kb*8+cg)*64 + lane)*8);
      a0 = __builtin_amdgcn_mfma_f32_16x16x32_bf16(av[0][kb], bhi, a0, 0,0,0);
      a1 = __builtin_amdgcn_mfma_f32_16x16x32_bf16(av[1][kb], bhi, a1, 0,0,0);
    }
    acc[0][cg]=a0; acc[1][cg]=a1;
  }
  v4f acc8[2] = {{0.f,0.f,0.f,0.f},{0.f,0.f,0.f,0.f}};
  #pragma unroll
  for(int kb=0;kb<4;++kb){
    v8bf bhi = *(const v8bf*)(whiE + (kb*64 + lane)*8);
    v8bf blo = *(const v8bf*)(wloE + (kb*64 + lane)*8);
    #pragma unroll
    for(int tt=0;tt<2;++tt){
      acc8[tt] = __builtin_amdgcn_mfma_f32_16x16x32_bf16(av[tt][kb], blo, acc8[tt], 0,0,0);
      acc8[tt] = __builtin_amdgcn_mfma_f32_16x16x32_bf16(av[tt][kb], bhi, acc8[tt], 0,0,0);
    }
  }
  #pragma unroll
  for(int tt=0;tt<2;++tt){
    #pragma unroll
    for(int m=0;m<4;++m){
      #pragma unroll
      for(int reg=0;reg<4;++reg){
        unsigned pack = (unsigned)f2bf_bits(acc[tt][2*m][reg]) | ((unsigned)f2bf_bits(acc[tt][2*m+1][reg])<<16);
        sxh[wave][tt][(q*4+reg)*68 + m*16 + r] = pack;
      }
    }
  }
  __syncthreads();
  {
    int rr = lane>>4, c4 = lane&15;
    #pragma unroll
    for(int tt=0;tt<2;++tt){
      #pragma unroll
      for(int rg=0; rg<4; ++rg){
        int i = rg*4 + rr;
        uint4 v = *(const uint4*)&sxh[wave][tt][i*68 + c4*4];
        *(uint4*)(xhb + (size_t)(r0[tt] + i)*64 + c4*4) = v;
      }
    }
  }
  #pragma unroll
  for(int tt=0;tt<2;++tt){
    if(r < 4){
      #pragma unroll
      for(int reg=0;reg<4;++reg)
        as_[(size_t)(r0[tt] + q*4 + reg)*4 + r] = acc8[tt][reg];
    } else if(r < 8){
      #pragma unroll
      for(int reg=0;reg<4;++reg)
        ad_[(size_t)(r0[tt] + q*4 + reg)*4 + (r-4)] = acc8[tt][reg];
    }
  }
}

// half-wave (32 lanes) per node, 8 nodes/block. Phase A: parallel softmax
// anchored at self-logit; deg<=8 single-round fast path (97.9% of nodes at
// Poisson(4)), deg<=16 two-round path, serial online-softmax for deg>16.
// All shuffle reductions use xor masks 4/8/16 (stay within the half-wave).
__global__ void k_aggr(const unsigned* __restrict__ xhb, const float* __restrict__ as_,
    const float* __restrict__ ad_, const float* __restrict__ ea_csr,
    const float* __restrict__ mebuf,
    const int* __restrict__ rowptr, const int* __restrict__ csr_src,
    const float* __restrict__ bnA_l, const float* __restrict__ bnS_l,
    unsigned* __restrict__ h16, int layer){
  __shared__ float lds_coef[8][16*4];
  __shared__ int   lds_src[8][16];
  int hw = threadIdx.x>>5, lh = threadIdx.x&31;
  int lane = threadIdx.x&63;
  int node = blockIdx.x*8 + hw;
  if(node >= N_NODES) return;
  int s = rowptr[node], e = rowptr[node+1];
  int deg = e - s;
  int hh2 = lh>>3;
  const uint2* xrow = (const uint2*)xhb;
  float a0,a1,a2,a3;

  if(deg <= 16){
    int eidx = lh>>2, h = lh&3;
    int li = layer*4+h;
    float mec0=mebuf[li], mec1=mebuf[16+li], mec2=mebuf[32+li], meb=mebuf[48+li];
    float ad_h = ad_[node*4+h];
    int j0 = eidx;
    float t0 = 0.f, g0 = 0.f;
    int s0 = node;
    bool v0 = (j0 < deg);
    if(v0){
      s0 = csr_src[s+j0];
      v4f qq = ((const v4f*)ea_csr)[s+j0];
      t0 = qq.x*mec0 + qq.y*mec1 + qq.z*mec2;
      g0 = lrelu(as_[s0*4+h] + ad_h + t0 + meb);
    }
    float ts, ds, inv;
    if(deg <= 8){
      ts = t0;
      ts += __shfl_xor(ts,4); ts += __shfl_xor(ts,8); ts += __shfl_xor(ts,16);
      float lt = (deg>0) ? ts/(float)deg + meb : 0.f;
      float al = lrelu(as_[node*4+h] + ad_h + lt);
      float e0 = v0 ? __expf(g0-al) : 0.f;
      ds = e0;
      ds += __shfl_xor(ds,4); ds += __shfl_xor(ds,8); ds += __shfl_xor(ds,16);
      inv = 1.f/(ds+1.f);
      if(h==0) lds_src[hw][j0] = s0;
      lds_coef[hw][j0*4+h] = e0*inv;
    } else {
      int j1 = 8+eidx;
      float t1 = 0.f, g1 = 0.f;
      int s1 = node;
      bool v1 = (j1 < deg);
      if(v1){
        s1 = csr_src[s+j1];
        v4f qq = ((const v4f*)ea_csr)[s+j1];
        t1 = qq.x*mec0 + qq.y*mec1 + qq.z*mec2;
        g1 = lrelu(as_[s1*4+h] + ad_h + t1 + meb);
      }
      ts = t0+t1;
      ts += __shfl_xor(ts,4); ts += __shfl_xor(ts,8); ts += __shfl_xor(ts,16);
      float lt = ts/(float)deg + meb;
      float al = lrelu(as_[node*4+h] + ad_h + lt);
      float e0 = v0 ? __expf(g0-al) : 0.f;
      float e1 = v1 ? __expf(g1-al) : 0.f;
      ds = e0+e1;
      ds += __shfl_xor(ds,4); ds += __shfl_xor(ds,8); ds += __shfl_xor(ds,16);
      inv = 1.f/(ds+1.f);
      if(h==0){ lds_src[hw][j0]=s0; lds_src[hw][j1]=s1; }
      lds_coef[hw][j0*4+h] = e0*inv;
      lds_coef[hw][j1*4+h] = e1*inv;
    }
    // ---- phase B ----
    float cs4 = __shfl(inv, (lane&32) | hh2);
    uint2 su = xrow[(size_t)node*32 + lh];
    int pdeg = (deg+1)&~1;
    a0=a1=a2=a3=0.f;
    for(int j=0;j<pdeg;j+=2){
      float ca = lds_coef[hw][j*4+hh2];
      float cb = lds_coef[hw][(j+1)*4+hh2];
      int sa = lds_src[hw][j], sb = lds_src[hw][j+1];
      uint2 ua = xrow[(size_t)sa*32+lh];
      uint2 ub = xrow[(size_t)sb*32+lh];
      a0 += ca*bflo(ua.x) + cb*bflo(ub.x);
      a1 += ca*bfhi(ua.x) + cb*bfhi(ub.x);
      a2 += ca*bflo(ua.y) + cb*bflo(ub.y);
      a3 += ca*bfhi(ua.y) + cb*bfhi(ub.y);
    }
    a0 += cs4*bflo(su.x); a1 += cs4*bfhi(su.x);
    a2 += cs4*bflo(su.y); a3 += cs4*bfhi(su.y);
  } else {
    // serial online-softmax path, runs on the half-wave's 32 lanes
    int li = layer*4+hh2;
    float mec0=mebuf[li], mec1=mebuf[16+li], mec2=mebuf[32+li], meb=mebuf[48+li];
    float adv = ad_[node*4+hh2];
    float ts = 0.f;
    for(int j=s;j<e;++j){
      v4f qq = ((const v4f*)ea_csr)[j];
      ts += qq.x*mec0 + qq.y*mec1 + qq.z*mec2;
    }
    float al = lrelu(as_[node*4+hh2] + adv + ts/(float)deg + meb);
    float m = al, d = 1.f;
    uint2 su = xrow[(size_t)node*32 + lh];
    float c0=bflo(su.x),c1=bfhi(su.x),c2=bflo(su.y),c3=bfhi(su.y);
    for(int j=s;j<e;++j){
      int sr = csr_src[j];
      v4f qq = ((const v4f*)ea_csr)[j];
      float b = lrelu(as_[sr*4+hh2] + adv + qq.x*mec0+qq.y*mec1+qq.z*mec2+meb);
      uint2 uv = xrow[(size_t)sr*32 + lh];
      float nm = fmaxf(m,b);
      float sc = __expf(m-nm), eb = __expf(b-nm);
      d = d*sc + eb;
      c0 = c0*sc + eb*bflo(uv.x); c1 = c1*sc + eb*bfhi(uv.x);
      c2 = c2*sc + eb*bflo(uv.y); c3 = c3*sc + eb*bfhi(uv.y);
      m = nm;
    }
    float inv2 = 1.f/d;
    a0=c0*inv2; a1=c1*inv2; a2=c2*inv2; a3=c3*inv2;
  }

  // epilogue: permuted folded BN + relu + bf16 residual; all 32 lanes active
  {
    const v4f* A4 = (const v4f*)bnA_l;
    const v4f* S4 = (const v4f*)bnS_l;
    v4f A = A4[lh], S = S4[lh];
    uint2 hr = ((const uint2*)h16)[(size_t)node*32 + lh];
    float o0 = fmaxf(a0*A.x+S.x, 0.f) + bflo(hr.x);
    float o1 = fmaxf(a1*A.y+S.y, 0.f) + bfhi(hr.x);
    float o2 = fmaxf(a2*A.z+S.z, 0.f) + bflo(hr.y);
    float o3 = fmaxf(a3*A.w+S.w, 0.f) + bfhi(hr.y);
    uint2 p;
    p.x = (unsigned)f2bf_bits(o0) | ((unsigned)f2bf_bits(o1)<<16);
    p.y = (unsigned)f2bf_bits(o2) | ((unsigned)f2bf_bits(o3)<<16);
    ((uint2*)h16)[(size_t)node*32 + lh] = p;
  }
}

// fused pool + head: 8 graphs/block, 256 blocks, 256 threads.
// Pooling: uint2 loads, 8 node-slots x 32 word-pairs (2KB/round coalesced),
// LDS tree-reduce, pooled vector written TRANSPOSED sgtT[k][g] (stride 12).
// MLP stages: thread owns output channel c, k-range split across 2 (or 4)
// groups, 8 per-graph accumulators -> each weight load amortized 8x and
// 8-way independent FMA chains (issue-bound, not latency-bound).
__global__ void k_tail(const unsigned* __restrict__ h16, const int* __restrict__ batch,
   const float* __restrict__ gf,
   const float* __restrict__ gc_w, const float* __restrict__ gc_b,
   const float* __restrict__ gf1_w, const float* __restrict__ gf1_b,
   const float* __restrict__ gf2_w, const float* __restrict__ gf2_b,
   const float* __restrict__ p1_w, const float* __restrict__ p1_b,
   const float* __restrict__ p2_w, const float* __restrict__ p2_b,
   const float* __restrict__ p3_w, const float* __restrict__ p3_b,
   float* __restrict__ out){
  __shared__ float sgtT[384*12];    // pooled [k][g], pad stride 12 (f4-aligned)
  __shared__ v4f   redA[256];       // pooling sum partials
  __shared__ v4f   redB[256];       // pooling max partials
  __shared__ float hid1s[8*64];
  __shared__ float combT[192*12];   // comb [k][g]
  __shared__ float partialb[8*128];
  __shared__ float r1T[128*12];
  __shared__ float ppb[3*8*64];
  __shared__ float r2T[64*12];
  __shared__ int   sbv[9];

  int t = threadIdx.x;
  int g0 = blockIdx.x*8;

  if(t < 9){
    int target = g0 + t;
    int lo=0, hi=N_NODES;
    while(lo<hi){ int mid=(lo+hi)>>1; if(batch[mid] < target) lo=mid+1; else hi=mid; }
    sbv[t]=lo;
  }
  __syncthreads();

  // ---- pooling ----
  {
    int w2 = t&31;      // uint2 word-pair index
    int j8 = t>>5;      // node slot 0..7
    const uint2* xr = (const uint2*)h16;
    for(int g=0; g<8; ++g){
      int s=sbv[g], e=sbv[g+1];
      float sl0=0.f,sh0=0.f,sl1=0.f,sh1=0.f;
      float ml0=-3.4e38f, mh0=-3.4e38f, ml1=-3.4e38f, mh1=-3.4e38f;
      for(int i=s+j8; i<e; i+=8){
        uint2 v = xr[(size_t)i*32 + w2];
        float a=bflo(v.x), b=bfhi(v.x), c=bflo(v.y), d=bfhi(v.y);
        sl0+=a; sh0+=b; sl1+=c; sh1+=d;
        ml0=fmaxf(ml0,a); mh0=fmaxf(mh0,b); ml1=fmaxf(ml1,c); mh1=fmaxf(mh1,d);
      }
      redA[t] = (v4f){sl0,sh0,sl1,sh1};
      redB[t] = (v4f){ml0,mh0,ml1,mh1};
      __syncthreads();
      if(t < 32){
        v4f S = redA[t], M = redB[t];
        #pragma unroll
        for(int jj=1; jj<8; ++jj){
          v4f a2 = redA[jj*32+t], b2 = redB[jj*32+t];
          S.x+=a2.x; S.y+=a2.y; S.z+=a2.z; S.w+=a2.w;
          M.x=fmaxf(M.x,b2.x); M.y=fmaxf(M.y,b2.y);
          M.z=fmaxf(M.z,b2.z); M.w=fmaxf(M.w,b2.w);
        }
        int cnt = sbv[g+1]-sbv[g];
        float invc = 1.f/(float)(cnt>1?cnt:1);
        if(cnt==0){ M.x=0.f; M.y=0.f; M.z=0.f; M.w=0.f; }
        // channels: words v0=2*w2, v1=2*w2+1; b=w2>>3, r=2*(w2&7)
        int bb = w2>>3, rr = (w2&7)*2;
        int c00 = bb*32+rr, c01=c00+16, c10=c00+1, c11=c00+17;
        sgtT[c00*12+g]=S.x*invc; sgtT[c01*12+g]=S.y*invc;
        sgtT[c10*12+g]=S.z*invc; sgtT[c11*12+g]=S.w*invc;
        sgtT[(128+c00)*12+g]=M.x; sgtT[(128+c01)*12+g]=M.y;
        sgtT[(128+c10)*12+g]=M.z; sgtT[(128+c11)*12+g]=M.w;
        sgtT[(256+c00)*12+g]=S.x; sgtT[(256+c01)*12+g]=S.y;
        sgtT[(256+c10)*12+g]=S.z; sgtT[(256+c11)*12+g]=S.w;
      }
      __syncthreads();
    }
  }

  // ---- glob hid1 (2 passes of 4 graphs) ----
  {
    int c=t&63, gg=t>>6;
    #pragma unroll
    for(int p=0;p<2;++p){
      int g = p*4+gg;
      float a = gf1_b[c];
      #pragma unroll
      for(int i=0;i<10;++i) a += gf[(size_t)(g0+g)*10+i]*gf1_w[i*64+c];
      hid1s[g*64+c] = fmaxf(a,0.f);
    }
  }

  // ---- gc: comb[:,0:128] (k split in 2 halves, 8 graph-accumulators) ----
  int c = t&127, half = t>>7;
  float acc[8];
  #pragma unroll
  for(int g=0;g<8;++g) acc[g]=0.f;
  {
    int kb = half*192;
    for(int kk=0; kk<192; ++kk){
      int k = kb+kk;
      float wv = gc_w[k*128+c];
      v4f s0v = *(const v4f*)&sgtT[k*12];
      v4f s1v = *(const v4f*)&sgtT[k*12+4];
      acc[0]+=s0v.x*wv; acc[1]+=s0v.y*wv; acc[2]+=s0v.z*wv; acc[3]+=s0v.w*wv;
      acc[4]+=s1v.x*wv; acc[5]+=s1v.y*wv; acc[6]+=s1v.z*wv; acc[7]+=s1v.w*wv;
    }
  }
  __syncthreads();   // hid1s visible

  // ---- gf2: comb[:,128:192] ----
  {
    int cc=t&63, gg=t>>6;
    #pragma unroll
    for(int p=0;p<2;++p){
      int g = p*4+gg;
      float a = gf2_b[cc];
      for(int k=0;k<64;++k) a += hid1s[g*64+k]*gf2_w[k*64+cc];
      combT[(128+cc)*12+g] = a;
    }
  }
  if(half==1){
    #pragma unroll
    for(int g=0;g<8;++g) partialb[g*128+c]=acc[g];
  }
  __syncthreads();
  if(half==0){
    float bias = gc_b[c];
    #pragma unroll
    for(int g=0;g<8;++g)
      combT[c*12+g] = fmaxf(acc[g]+partialb[g*128+c]+bias, 0.f);
  }
  __syncthreads();

  // ---- p1: r1 = relu(comb @ p1_w) ----
  float a1[8];
  #pragma unroll
  for(int g=0;g<8;++g) a1[g]=0.f;
  {
    int kb = half*96;
    for(int kk=0; kk<96; ++kk){
      int k = kb+kk;
      float wv = p1_w[k*128+c];
      v4f s0v = *(const v4f*)&combT[k*12];
      v4f s1v = *(const v4f*)&combT[k*12+4];
      a1[0]+=s0v.x*wv; a1[1]+=s0v.y*wv; a1[2]+=s0v.z*wv; a1[3]+=s0v.w*wv;
      a1[4]+=s1v.x*wv; a1[5]+=s1v.y*wv; a1[6]+=s1v.z*wv; a1[7]+=s1v.w*wv;
    }
  }
  if(half==1){
    #pragma unroll
    for(int g=0;g<8;++g) partialb[g*128+c]=a1[g];
  }
  __syncthreads();
  if(half==0){
    float b1 = p1_b[c];
    #pragma unroll
    for(int g=0;g<8;++g)
      r1T[c*12+g] = fmaxf(a1[g]+partialb[g*128+c]+b1, 0.f);
  }
  __syncthreads();

  // ---- p2: r2 = relu(r1 @ p2_w), k split in 4 quarters ----
  {
    int c2=t&63, qd=t>>6;
    float a2[8];
    #pragma unroll
    for(int g=0;g<8;++g) a2[g]=0.f;
    int kb = qd*32;
    for(int kk=0; kk<32; ++kk){
      int k = kb+kk;
      float wv = p2_w[k*64+c2];
      v4f s0v = *(const v4f*)&r1T[k*12];
      v4f s1v = *(const v4f*)&r1T[k*12+4];
      a2[0]+=s0v.x*wv; a2[1]+=s0v.y*wv; a2[2]+=s0v.z*wv; a2[3]+=s0v.w*wv;
      a2[4]+=s1v.x*wv; a2[5]+=s1v.y*wv; a2[6]+=s1v.z*wv; a2[7]+=s1v.w*wv;
    }
    if(qd>0){
      #pragma unroll
      for(int g=0;g<8;++g) ppb[((qd-1)*8+g)*64+c2]=a2[g];
    }
    __syncthreads();
    if(qd==0){
      float b2 = p2_b[c2];
      #pragma unroll
      for(int g=0;g<8;++g){
        float v = a2[g] + ppb[g*64+c2] + ppb[(8+g)*64+c2] + ppb[(16+g)*64+c2] + b2;
        r2T[c2*12+g] = fmaxf(v,0.f);
      }
    }
    __syncthreads();
  }

  // ---- p3 ----
  if(t < 40){
    int g = t/5, o = t%5;
    float a = p3_b[o];
    for(int k=0;k<64;++k) a += r2T[k*12+g]*p3_w[k*TOUT+o];
    out[(size_t)(g0+g)*TOUT+o] = a;
  }
}

extern "C" void kernel_launch(void* const* d_in, const int* in_sizes, int n_in,
                              void* d_out, int out_size, void* d_ws, size_t ws_size,
                              hipStream_t stream){
  (void)in_sizes; (void)n_in; (void)out_size; (void)ws_size;
  const float* x        = (const float*)d_in[0];
  const int*   ei       = (const int*)d_in[1];
  const float* ea       = (const float*)d_in[2];
  const int*   batch    = (const int*)d_in[3];
  const float* gfin     = (const float*)d_in[4];
  const float* node_w   = (const float*)d_in[5];
  const float* node_b   = (const float*)d_in[6];
  const float* edge_w   = (const float*)d_in[7];
  const float* edge_b   = (const float*)d_in[8];
  const float* gat_lin_w  = (const float*)d_in[9];
  const float* gat_edge_w = (const float*)d_in[10];
  const float* att_src  = (const float*)d_in[11];
  const float* att_dst  = (const float*)d_in[12];
  const float* att_edge = (const float*)d_in[13];
  const float* gat_bias = (const float*)d_in[14];
  const float* bn_gamma = (const float*)d_in[15];
  const float* bn_beta  = (const float*)d_in[16];
  const float* bn_mean  = (const float*)d_in[17];
  const float* bn_var   = (const float*)d_in[18];
  const float* gc_w = (const float*)d_in[19];
  const float* gc_b = (const float*)d_in[20];
  const float* gf1_w = (const float*)d_in[21];
  const float* gf1_b = (const float*)d_in[22];
  const float* gf2_w = (const float*)d_in[23];
  const float* gf2_b = (const float*)d_in[24];
  const float* p1_w = (const float*)d_in[25];
  const float* p1_b = (const float*)d_in[26];
  const float* p2_w = (const float*)d_in[27];
  const float* p2_b = (const float*)d_in[28];
  const float* p3_w = (const float*)d_in[29];
  const float* p3_b = (const float*)d_in[30];
  float* out = (float*)d_out;

  char* w = (char*)d_ws;
  size_t o = 0;
  auto carve = [&](size_t bytes)->char*{
    char* p = w + o; o += (bytes + 255) & ~(size_t)255; return p;
  };
  unsigned* xhb = (unsigned*)carve((size_t)N_NODES*64*4);
  unsigned* h16 = (unsigned*)carve((size_t)N_NODES*64*4);
  float* ea_csr = (float*)carve((size_t)N_EDGES*4*4);
  float* as_    = (float*)carve((size_t)N_NODES*4*4);
  float* ad_    = (float*)carve((size_t)N_NODES*4*4);
  int* deg      = (int*)carve((size_t)N_NODES*4);
  int* rowptr   = (int*)carve((size_t)(N_NODES+1)*4);
  int* fill     = (int*)carve((size_t)N_NODES*4);
  int* csr_src  = (int*)carve((size_t)N_EDGES*4);
  int* part     = (int*)carve(1024*4);
  float* mebuf  = (float*)carve(64*4);
  float* bnA    = (float*)carve((size_t)NLAYER*HID*4);
  float* bnS    = (float*)carve((size_t)NLAYER*HID*4);
  unsigned short* whi = (unsigned short*)carve(65536*2);
  unsigned short* whiE = (unsigned short*)carve(8192*2);
  unsigned short* wloE = (unsigned short*)carve(8192*2);

  // setup: mebuf + BNfold + w_ext + wswz + zero(deg,fill) + hinit
  k_setup<<<1688 + N_NODES/4, 256, 0, stream>>>(gat_edge_w, att_edge, edge_w, edge_b,
        gat_bias, bn_gamma, bn_beta, bn_mean, bn_var,
        gat_lin_w, att_src, att_dst, x, node_w, node_b, h16,
        mebuf, bnA, bnS, whiE, wloE, whi, deg, fill);
  k_deg<<<(N_EDGES+255)/256, 256, 0, stream>>>(ei, deg);
  k_scan1<<<NB,256,0,stream>>>(deg, part);
  k_scan3<<<NB,256,0,stream>>>(deg, part, rowptr);

  for(int l=0;l<NLAYER;++l){
    int gb = (l==0) ? GEMM_BLOCKS + (N_EDGES+255)/256 : GEMM_BLOCKS;
    k_gemm<<<gb,256,0,stream>>>((const unsigned short*)h16,
        whi + l*16384, whiE + l*2048, wloE + l*2048,
        xhb, as_, ad_, ei, ea, rowptr, fill, csr_src, ea_csr);
    k_aggr<<<(N_NODES+7)/8,256,0,stream>>>(xhb, as_, ad_, ea_csr, mebuf,
        rowptr, csr_src, bnA + l*128, bnS + l*128, h16, l);
  }

  k_tail<<<N_GRAPHS/8,256,0,stream>>>(h16, batch, gfin, gc_w, gc_b, gf1_w, gf1_b,
        gf2_w, gf2_b, p1_w, p1_b, p2_w, p2_b, p3_w, p3_b, out);
}

// Round 4
// 422.941 us; speedup vs baseline: 1.1609x; 1.0233x over previous
//
#include <hip/hip_runtime.h>

#define N_NODES 100000
#define N_EDGES 400000
#define N_GRAPHS 2048
#define HID 128
#define NLAYER 4
#define TOUT 5
#define EPSV 1e-5f
#define SLOPE 0.2f
#define NB 98   // (N_NODES+1023)/1024
#define GEMM_BLOCKS 782  // (N_NODES+127)/128

typedef float v4f __attribute__((ext_vector_type(4)));
typedef float v2f __attribute__((ext_vector_type(2)));
typedef __bf16 v8bf __attribute__((ext_vector_type(8)));

static __device__ __forceinline__ unsigned short f2bf_bits(float f){
  unsigned u = __builtin_bit_cast(unsigned, f);
  unsigned r = u + 0x7fffu + ((u >> 16) & 1u);
  return (unsigned short)(r >> 16);
}
static __device__ __forceinline__ float bfbits2f(unsigned short s){
  unsigned u = ((unsigned)s) << 16;
  return __builtin_bit_cast(float, u);
}
static __device__ __forceinline__ float bflo(unsigned u){
  return __builtin_bit_cast(float, u << 16);
}
static __device__ __forceinline__ float bfhi(unsigned u){
  return __builtin_bit_cast(float, u & 0xffff0000u);
}
static __device__ __forceinline__ float lrelu(float v){
  return v>0.f ? v : SLOPE*v;
}

// Physical bf16 layout (head-aligned pairing):
//   word u (0..63): b=u>>4, r=u&15 -> holds channels (b*32+r [lo], b*32+16+r [hi]).
//   Lane l (words 2l,2l+1) is entirely head l>>3.
//   contraction position for channel k: kp = (k>>5)*32 + (k&15)*2 + ((k>>4)&1).

// merged setup:
//  blocks 0..15      : mebuf direct (wave-per-output, parallel)
//  block  16         : BN fold
//  blocks 17..1040   : w_ext (split hi/lo)
//  blocks 1041..1296 : wswz (single bf16 W)
//  blocks 1297..1687 : zero deg/fill
//  blocks 1688..     : hinit
__global__ void k_setup(const float* __restrict__ gat_edge_w, const float* __restrict__ att_edge,
                        const float* __restrict__ edge_w, const float* __restrict__ edge_b,
                        const float* __restrict__ gat_bias, const float* __restrict__ gamma,
                        const float* __restrict__ beta, const float* __restrict__ mean,
                        const float* __restrict__ var, const float* __restrict__ gat_lin_w,
                        const float* __restrict__ att_src, const float* __restrict__ att_dst,
                        const float* __restrict__ x, const float* __restrict__ nw,
                        const float* __restrict__ nb, unsigned* __restrict__ h16,
                        float* __restrict__ mebuf, float* __restrict__ bnA, float* __restrict__ bnS,
                        unsigned short* __restrict__ whiE, unsigned short* __restrict__ wloE,
                        unsigned short* __restrict__ whi,
                        int* __restrict__ deg, int* __restrict__ fill){
  int bid = blockIdx.x, t = threadIdx.x;
  if(bid < 16){
    // mebuf[o], o = bid*4 + wave; o<48: edge_w row f=o>>4; o>=48: edge_b
    int wv = t>>6, lane = t&63;
    int o = bid*4 + wv;
    int li = (o<48)? (o&15) : (o-48);
    int f = o>>4;
    int l = li>>2, hh = li&3;
    int c = lane&31, kk = lane>>5;
    float at_c = att_edge[l*128 + hh*32 + c];
    float acc = 0.f;
    #pragma unroll 8
    for(int t2=0; t2<64; ++t2){
      int k = kk*64 + t2;
      float wk = (o<48)? edge_w[f*128+k] : edge_b[k];
      acc += wk * gat_edge_w[l*16384 + k*128 + hh*32 + c];
    }
    acc *= at_c;
    acc += __shfl_xor(acc,1); acc += __shfl_xor(acc,2); acc += __shfl_xor(acc,4);
    acc += __shfl_xor(acc,8); acc += __shfl_xor(acc,16); acc += __shfl_xor(acc,32);
    if(lane==0) mebuf[o] = acc;
  } else if(bid == 16){
    for(int i=t; i<NLAYER*HID; i+=256){
      int l_ = i>>7, pos = i&127, lane = pos>>2, j = pos&3;
      int ch = ((lane>>3)<<5) + ((lane&7)<<1) + ((j&1)<<4) + (j>>1);
      int src = l_*128 + ch;
      float A = gamma[src]*rsqrtf(var[src]+EPSV);
      bnA[i] = A;
      bnS[i] = (gat_bias[src]-mean[src])*A + beta[src];
    }
  } else if(bid <= 1040){
    int wave = t>>6, lane = t&63;
    int i = (bid-17)*8 + wave*2 + (lane>>5);   // 0..8191
    int l_ = i>>11, rest = i&2047, kp = rest>>4, col = rest&15;
    int sub = lane&31;
    float val = 0.f;
    if(col < 8){
      int h_ = col&3, isdst = col>>2;
      int ch = ((kp>>5)<<5) + ((kp&1)<<4) + ((kp&31)>>1);
      const float* at = (isdst? att_dst : att_src);
      val = gat_lin_w[l_*16384 + ch*128 + h_*32 + sub] * at[l_*128 + h_*32 + sub];
    }
    val += __shfl_xor(val,1); val += __shfl_xor(val,2); val += __shfl_xor(val,4);
    val += __shfl_xor(val,8); val += __shfl_xor(val,16);
    if(sub == 0){
      unsigned short hi = f2bf_bits(val);
      unsigned short lo = f2bf_bits(val - bfbits2f(hi));
      int kb=kp>>5, quad=(kp>>3)&3, jj=kp&7, lane2=quad*16+col;
      int dst = ((l_*4+kb)*64 + lane2)*8 + jj;
      whiE[dst]=hi; wloE[dst]=lo;
    }
  } else if(bid <= 1296){
    int tg = (bid-1041)*256 + t;              // 0..65535 == dst index
    int base = tg>>9, off = tg&511;
    int l = base>>5, kb=(base>>3)&3, cg=base&7;
    int lane = off>>3, j = off&7;
    int quad = lane>>4, r = lane&15;
    int kp = kb*32 + quad*8 + j;
    int k = ((kp>>5)<<5) | ((kp&1)<<4) | ((kp&31)>>1);
    whi[tg] = f2bf_bits(gat_lin_w[l*16384 + k*128 + cg*16 + r]);
  } else if(bid <= 1687){
    int tg = (bid-1297)*256 + t;
    if(tg < N_NODES){ deg[tg]=0; fill[tg]=0; }
  } else {
    int node = (bid-1688)*4 + (t>>6);
    int c = t&63;
    int ch = ((c>>4)<<5) + (c&15);
    float a0 = nb[ch], a1 = nb[ch+16];
    #pragma unroll
    for(int f=0; f<7; ++f){
      float xv = x[node*7+f];
      a0 += xv*nw[f*HID+ch];
      a1 += xv*nw[f*HID+ch+16];
    }
    unsigned p = (unsigned)f2bf_bits(a0) | ((unsigned)f2bf_bits(a1)<<16);
    h16[(size_t)node*64 + c] = p;
  }
}

// deg count only (after zeroing in k_setup)
__global__ void k_deg(const int* __restrict__ ei, int* __restrict__ deg){
  int e = blockIdx.x*256 + threadIdx.x;
  if(e < N_EDGES) atomicAdd(&deg[ei[N_EDGES+e]], 1);
}

// scan phase 1: per-chunk sums
__global__ void k_scan1(const int* __restrict__ deg, int* __restrict__ part){
  __shared__ int s[256];
  int t=threadIdx.x; int base = blockIdx.x*1024 + t*4;
  int sum=0;
  #pragma unroll
  for(int j=0;j<4;++j){ int i=base+j; sum += (i<N_NODES)? deg[i]:0; }
  s[t]=sum; __syncthreads();
  for(int off=128; off>0; off>>=1){ if(t<off) s[t]+=s[t+off]; __syncthreads(); }
  if(t==0) part[blockIdx.x]=s[0];
}
// scan phase 2+3 fused
__global__ void k_scan3(const int* __restrict__ deg, const int* __restrict__ part,
                        int* __restrict__ rowptr){
  __shared__ int s[256];
  int t=threadIdx.x, b=blockIdx.x;
  int g = 0, tot = 0;
  for(int i=0;i<NB;++i){ int v = part[i]; g += (i<b)? v : 0; tot += v; }
  if(b==0 && t==0) rowptr[N_NODES]=tot;
  int base = b*1024 + t*4;
  int v[4]; int sum=0; int pre[4];
  #pragma unroll
  for(int j=0;j<4;++j){ int i=base+j; v[j]=(i<N_NODES)?deg[i]:0; pre[j]=sum; sum+=v[j]; }
  s[t]=sum; __syncthreads();
  for(int off=1; off<256; off<<=1){
    int xv = (t>=off)? s[t-off]:0; __syncthreads();
    s[t]+=xv; __syncthreads();
  }
  int toff = (t>0)? s[t-1]:0;
  #pragma unroll
  for(int j=0;j<4;++j){ int i=base+j; if(i<N_NODES) rowptr[i]=g+toff+pre[j]; }
}

// xh = h16 @ W[l], 2 row-tiles per wave; as_/ad_ via split-precision w_ext tile.
// LDS-staged coalesced stores. Layer-0 launch carries extra blocks that build
// the CSR (fill) — uniform per-block branch, no data conflicts.
__global__ void k_gemm(const unsigned short* __restrict__ h16,
                       const unsigned short* __restrict__ whi,
                       const unsigned short* __restrict__ whiE,
                       const unsigned short* __restrict__ wloE,
                       unsigned* __restrict__ xhb, float* __restrict__ as_, float* __restrict__ ad_,
                       const int* __restrict__ ei, const float* __restrict__ ea,
                       const int* __restrict__ rowptr, int* __restrict__ fill,
                       int* __restrict__ csr_src, float* __restrict__ ea_csr){
  if(blockIdx.x >= GEMM_BLOCKS){
    int e = (blockIdx.x - GEMM_BLOCKS)*256 + threadIdx.x;
    if(e < N_EDGES){
      int dst = ei[N_EDGES+e];
      int pos = rowptr[dst] + atomicAdd(&fill[dst],1);
      csr_src[pos] = ei[e];
      v4f q = {ea[e*3], ea[e*3+1], ea[e*3+2], 0.f};
      ((v4f*)ea_csr)[pos] = q;
    }
    return;
  }
  __shared__ unsigned sxh[4][2][16*68];
  int wave = threadIdx.x>>6, lane = threadIdx.x&63;
  int base = blockIdx.x*128;
  int q = lane>>4, r = lane&15;
  int r0[2];
  r0[0] = base + wave*16;
  r0[1] = base + 64 + wave*16;
  if(r0[0] > N_NODES-16) r0[0] = N_NODES-16;
  if(r0[1] > N_NODES-16) r0[1] = N_NODES-16;
  v8bf av[2][4];
  #pragma unroll
  for(int tt=0;tt<2;++tt){
    const unsigned short* hrow = h16 + (size_t)(r0[tt] + r)*HID;
    #pragma unroll
    for(int kb=0;kb<4;++kb)
      av[tt][kb] = *(const v8bf*)(hrow + kb*32 + q*8);
  }
  v4f acc[2][8];
  #pragma unroll
  for(int cg=0;cg<8;++cg){
    v4f a0 = {0.f,0.f,0.f,0.f}, a1 = {0.f,0.f,0.f,0.f};
    #pragma unroll
    for(int kb=0;kb<4;++kb){
      v8bf bhi = *(const v8bf*)(whi + ((kb*8+cg)*64 + lane)*8);
      a0 = __builtin_amdgcn_mfma_f32_16x16x32_bf16(av[0][kb], bhi, a0, 0,0,0);
      a1 = __builtin_amdgcn_mfma_f32_16x16x32_bf16(av[1][kb], bhi, a1, 0,0,0);
    }
    acc[0][cg]=a0; acc[1][cg]=a1;
  }
  v4f acc8[2] = {{0.f,0.f,0.f,0.f},{0.f,0.f,0.f,0.f}};
  #pragma unroll
  for(int kb=0;kb<4;++kb){
    v8bf bhi = *(const v8bf*)(whiE + (kb*64 + lane)*8);
    v8bf blo = *(const v8bf*)(wloE + (kb*64 + lane)*8);
    #pragma unroll
    for(int tt=0;tt<2;++tt){
      acc8[tt] = __builtin_amdgcn_mfma_f32_16x16x32_bf16(av[tt][kb], blo, acc8[tt], 0,0,0);
      acc8[tt] = __builtin_amdgcn_mfma_f32_16x16x32_bf16(av[tt][kb], bhi, acc8[tt], 0,0,0);
    }
  }
  #pragma unroll
  for(int tt=0;tt<2;++tt){
    #pragma unroll
    for(int m=0;m<4;++m){
      #pragma unroll
      for(int reg=0;reg<4;++reg){
        unsigned pack = (unsigned)f2bf_bits(acc[tt][2*m][reg]) | ((unsigned)f2bf_bits(acc[tt][2*m+1][reg])<<16);
        sxh[wave][tt][(q*4+reg)*68 + m*16 + r] = pack;
      }
    }
  }
  __syncthreads();
  {
    int rr = lane>>4, c4 = lane&15;
    #pragma unroll
    for(int tt=0;tt<2;++tt){
      #pragma unroll
      for(int rg=0; rg<4; ++rg){
        int i = rg*4 + rr;
        uint4 v = *(const uint4*)&sxh[wave][tt][i*68 + c4*4];
        *(uint4*)(xhb + (size_t)(r0[tt] + i)*64 + c4*4) = v;
      }
    }
  }
  #pragma unroll
  for(int tt=0;tt<2;++tt){
    if(r < 4){
      #pragma unroll
      for(int reg=0;reg<4;++reg)
        as_[(size_t)(r0[tt] + q*4 + reg)*4 + r] = acc8[tt][reg];
    } else if(r < 8){
      #pragma unroll
      for(int reg=0;reg<4;++reg)
        ad_[(size_t)(r0[tt] + q*4 + reg)*4 + (r-4)] = acc8[tt][reg];
    }
  }
}

// half-wave (32 lanes) per node, 8 nodes/block. Phase A: parallel softmax
// anchored at self-logit; deg<=8 single-round fast path (97.9% of nodes at
// Poisson(4)), deg<=16 two-round path, serial online-softmax for deg>16.
// All shuffle reductions use xor masks 4/8/16 (stay within the half-wave).
__global__ void k_aggr(const unsigned* __restrict__ xhb, const float* __restrict__ as_,
    const float* __restrict__ ad_, const float* __restrict__ ea_csr,
    const float* __restrict__ mebuf,
    const int* __restrict__ rowptr, const int* __restrict__ csr_src,
    const float* __restrict__ bnA_l, const float* __restrict__ bnS_l,
    unsigned* __restrict__ h16, int layer){
  __shared__ float lds_coef[8][16*4];
  __shared__ int   lds_src[8][16];
  int hw = threadIdx.x>>5, lh = threadIdx.x&31;
  int lane = threadIdx.x&63;
  int node = blockIdx.x*8 + hw;
  if(node >= N_NODES) return;
  int s = rowptr[node], e = rowptr[node+1];
  int deg = e - s;
  int hh2 = lh>>3;
  const uint2* xrow = (const uint2*)xhb;
  float a0,a1,a2,a3;

  if(deg <= 16){
    int eidx = lh>>2, h = lh&3;
    int li = layer*4+h;
    float mec0=mebuf[li], mec1=mebuf[16+li], mec2=mebuf[32+li], meb=mebuf[48+li];
    float ad_h = ad_[node*4+h];
    int j0 = eidx;
    float t0 = 0.f, g0 = 0.f;
    int s0 = node;
    bool v0 = (j0 < deg);
    if(v0){
      s0 = csr_src[s+j0];
      v4f qq = ((const v4f*)ea_csr)[s+j0];
      t0 = qq.x*mec0 + qq.y*mec1 + qq.z*mec2;
      g0 = lrelu(as_[s0*4+h] + ad_h + t0 + meb);
    }
    float ts, ds, inv;
    if(deg <= 8){
      ts = t0;
      ts += __shfl_xor(ts,4); ts += __shfl_xor(ts,8); ts += __shfl_xor(ts,16);
      float lt = (deg>0) ? ts/(float)deg + meb : 0.f;
      float al = lrelu(as_[node*4+h] + ad_h + lt);
      float e0 = v0 ? __expf(g0-al) : 0.f;
      ds = e0;
      ds += __shfl_xor(ds,4); ds += __shfl_xor(ds,8); ds += __shfl_xor(ds,16);
      inv = 1.f/(ds+1.f);
      if(h==0) lds_src[hw][j0] = s0;
      lds_coef[hw][j0*4+h] = e0*inv;
    } else {
      int j1 = 8+eidx;
      float t1 = 0.f, g1 = 0.f;
      int s1 = node;
      bool v1 = (j1 < deg);
      if(v1){
        s1 = csr_src[s+j1];
        v4f qq = ((const v4f*)ea_csr)[s+j1];
        t1 = qq.x*mec0 + qq.y*mec1 + qq.z*mec2;
        g1 = lrelu(as_[s1*4+h] + ad_h + t1 + meb);
      }
      ts = t0+t1;
      ts += __shfl_xor(ts,4); ts += __shfl_xor(ts,8); ts += __shfl_xor(ts,16);
      float lt = ts/(float)deg + meb;
      float al = lrelu(as_[node*4+h] + ad_h + lt);
      float e0 = v0 ? __expf(g0-al) : 0.f;
      float e1 = v1 ? __expf(g1-al) : 0.f;
      ds = e0+e1;
      ds += __shfl_xor(ds,4); ds += __shfl_xor(ds,8); ds += __shfl_xor(ds,16);
      inv = 1.f/(ds+1.f);
      if(h==0){ lds_src[hw][j0]=s0; lds_src[hw][j1]=s1; }
      lds_coef[hw][j0*4+h] = e0*inv;
      lds_coef[hw][j1*4+h] = e1*inv;
    }
    // ---- phase B ----
    float cs4 = __shfl(inv, (lane&32) | hh2);
    uint2 su = xrow[(size_t)node*32 + lh];
    int pdeg = (deg+1)&~1;
    a0=a1=a2=a3=0.f;
    for(int j=0;j<pdeg;j+=2){
      float ca = lds_coef[hw][j*4+hh2];
      float cb = lds_coef[hw][(j+1)*4+hh2];
      int sa = lds_src[hw][j], sb = lds_src[hw][j+1];
      uint2 ua = xrow[(size_t)sa*32+lh];
      uint2 ub = xrow[(size_t)sb*32+lh];
      a0 += ca*bflo(ua.x) + cb*bflo(ub.x);
      a1 += ca*bfhi(ua.x) + cb*bfhi(ub.x);
      a2 += ca*bflo(ua.y) + cb*bflo(ub.y);
      a3 += ca*bfhi(ua.y) + cb*bfhi(ub.y);
    }
    a0 += cs4*bflo(su.x); a1 += cs4*bfhi(su.x);
    a2 += cs4*bflo(su.y); a3 += cs4*bfhi(su.y);
  } else {
    // serial online-softmax path, runs on the half-wave's 32 lanes
    int li = layer*4+hh2;
    float mec0=mebuf[li], mec1=mebuf[16+li], mec2=mebuf[32+li], meb=mebuf[48+li];
    float adv = ad_[node*4+hh2];
    float ts = 0.f;
    for(int j=s;j<e;++j){
      v4f qq = ((const v4f*)ea_csr)[j];
      ts += qq.x*mec0 + qq.y*mec1 + qq.z*mec2;
    }
    float al = lrelu(as_[node*4+hh2] + adv + ts/(float)deg + meb);
    float m = al, d = 1.f;
    uint2 su = xrow[(size_t)node*32 + lh];
    float c0=bflo(su.x),c1=bfhi(su.x),c2=bflo(su.y),c3=bfhi(su.y);
    for(int j=s;j<e;++j){
      int sr = csr_src[j];
      v4f qq = ((const v4f*)ea_csr)[j];
      float b = lrelu(as_[sr*4+hh2] + adv + qq.x*mec0+qq.y*mec1+qq.z*mec2+meb);
      uint2 uv = xrow[(size_t)sr*32 + lh];
      float nm = fmaxf(m,b);
      float sc = __expf(m-nm), eb = __expf(b-nm);
      d = d*sc + eb;
      c0 = c0*sc + eb*bflo(uv.x); c1 = c1*sc + eb*bfhi(uv.x);
      c2 = c2*sc + eb*bflo(uv.y); c3 = c3*sc + eb*bfhi(uv.y);
      m = nm;
    }
    float inv2 = 1.f/d;
    a0=c0*inv2; a1=c1*inv2; a2=c2*inv2; a3=c3*inv2;
  }

  // epilogue: permuted folded BN + relu + bf16 residual; all 32 lanes active
  {
    const v4f* A4 = (const v4f*)bnA_l;
    const v4f* S4 = (const v4f*)bnS_l;
    v4f A = A4[lh], S = S4[lh];
    uint2 hr = ((const uint2*)h16)[(size_t)node*32 + lh];
    float o0 = fmaxf(a0*A.x+S.x, 0.f) + bflo(hr.x);
    float o1 = fmaxf(a1*A.y+S.y, 0.f) + bfhi(hr.x);
    float o2 = fmaxf(a2*A.z+S.z, 0.f) + bflo(hr.y);
    float o3 = fmaxf(a3*A.w+S.w, 0.f) + bfhi(hr.y);
    uint2 p;
    p.x = (unsigned)f2bf_bits(o0) | ((unsigned)f2bf_bits(o1)<<16);
    p.y = (unsigned)f2bf_bits(o2) | ((unsigned)f2bf_bits(o3)<<16);
    ((uint2*)h16)[(size_t)node*32 + lh] = p;
  }
}

// pooling: one block per graph, 256 threads (8 node-slots x 32 uint2 words).
// Full-occupancy streaming read of h16; writes pooled [N_GRAPHS][384] fp32
// in ORIGINAL channel order via float2 stores (mean | max | sum sections).
__global__ void k_pool(const unsigned* __restrict__ h16, const int* __restrict__ batch,
                       float* __restrict__ pool){
  __shared__ v4f redA[256];
  __shared__ v4f redB[256];
  __shared__ int sbp[2];
  int t = threadIdx.x, g = blockIdx.x;
  if(t < 2){
    int target = g + t;
    int lo=0, hi=N_NODES;
    while(lo<hi){ int mid=(lo+hi)>>1; if(batch[mid] < target) lo=mid+1; else hi=mid; }
    sbp[t]=lo;
  }
  __syncthreads();
  int s = sbp[0], e = sbp[1];
  int w2 = t&31, j8 = t>>5;
  const uint2* xr = (const uint2*)h16;
  float sl0=0.f,sh0=0.f,sl1=0.f,sh1=0.f;
  float ml0=-3.4e38f, mh0=-3.4e38f, ml1=-3.4e38f, mh1=-3.4e38f;
  for(int i=s+j8; i<e; i+=8){
    uint2 v = xr[(size_t)i*32 + w2];
    float a=bflo(v.x), b=bfhi(v.x), c=bflo(v.y), d=bfhi(v.y);
    sl0+=a; sh0+=b; sl1+=c; sh1+=d;
    ml0=fmaxf(ml0,a); mh0=fmaxf(mh0,b); ml1=fmaxf(ml1,c); mh1=fmaxf(mh1,d);
  }
  redA[t] = (v4f){sl0,sh0,sl1,sh1};
  redB[t] = (v4f){ml0,mh0,ml1,mh1};
  __syncthreads();
  if(t < 32){
    v4f S = redA[t], M = redB[t];
    #pragma unroll
    for(int jj=1; jj<8; ++jj){
      v4f a2 = redA[jj*32+t], b2 = redB[jj*32+t];
      S.x+=a2.x; S.y+=a2.y; S.z+=a2.z; S.w+=a2.w;
      M.x=fmaxf(M.x,b2.x); M.y=fmaxf(M.y,b2.y);
      M.z=fmaxf(M.z,b2.z); M.w=fmaxf(M.w,b2.w);
    }
    int cnt = e-s;
    float invc = 1.f/(float)(cnt>1?cnt:1);
    if(cnt==0){ M.x=0.f; M.y=0.f; M.z=0.f; M.w=0.f; }
    // channel map: c00=(w2>>3)*32+(w2&7)*2 ; pairs (c00,c00+1) and (c00+16,c00+17)
    int c00 = (w2>>3)*32 + (w2&7)*2;
    float* pg = pool + (size_t)g*384;
    *(v2f*)&pg[c00]        = (v2f){S.x*invc, S.z*invc};
    *(v2f*)&pg[c00+16]     = (v2f){S.y*invc, S.w*invc};
    *(v2f*)&pg[128+c00]    = (v2f){M.x, M.z};
    *(v2f*)&pg[128+c00+16] = (v2f){M.y, M.w};
    *(v2f*)&pg[256+c00]    = (v2f){S.x, S.z};
    *(v2f*)&pg[256+c00+16] = (v2f){S.y, S.w};
  }
}

// head MLP: 4 graphs/block, 512 blocks (2 blocks/CU, 8 waves/CU).
// Pooled tile staged in LDS poolT[k][4] (v4f broadcast reads). Each stage's
// k-loop manually unrolled x4 with batched weight loads (>=4 loads in flight).
__global__ void k_head(const float* __restrict__ pool,
   const float* __restrict__ gf,
   const float* __restrict__ gc_w, const float* __restrict__ gc_b,
   const float* __restrict__ gf1_w, const float* __restrict__ gf1_b,
   const float* __restrict__ gf2_w, const float* __restrict__ gf2_b,
   const float* __restrict__ p1_w, const float* __restrict__ p1_b,
   const float* __restrict__ p2_w, const float* __restrict__ p2_b,
   const float* __restrict__ p3_w, const float* __restrict__ p3_b,
   float* __restrict__ out){
  __shared__ float poolT[384*4];   // [k][g]
  __shared__ float hid1s[64*4];
  __shared__ float partial[128*4]; // v4f per c
  __shared__ float combT[192*4];
  __shared__ float r1T[128*4];
  __shared__ float ppb[3*64*4];
  __shared__ float r2T[64*4];
  int t = threadIdx.x;
  int g0 = blockIdx.x*4;

  // stage pooled tile: poolT[k*4+g] = pool[(g0+g)*384+k]
  for(int idx=t; idx<1536; idx+=256)
    poolT[idx] = pool[(size_t)(g0+(idx&3))*384 + (idx>>2)];
  // glob hid1 (no dep on poolT)
  {
    int c=t&63, g=t>>6;
    float a = gf1_b[c];
    #pragma unroll
    for(int i=0;i<10;++i) a += gf[(size_t)(g0+g)*10+i]*gf1_w[i*64+c];
    hid1s[c*4+g] = fmaxf(a,0.f);
  }
  __syncthreads();

  int c = t&127, half = t>>7;
  const v4f* poolv = (const v4f*)poolT;
  const v4f* combv = (const v4f*)combT;
  const v4f* r1v = (const v4f*)r1T;

  // ---- gc: 384-k split in 2 halves of 192, unroll 4 ----
  v4f acc = {0.f,0.f,0.f,0.f};
  {
    int kb = half*192;
    for(int kk=0; kk<192; kk+=4){
      int k = kb+kk;
      float w0 = gc_w[(k+0)*128+c];
      float w1 = gc_w[(k+1)*128+c];
      float w2 = gc_w[(k+2)*128+c];
      float w3 = gc_w[(k+3)*128+c];
      v4f p0=poolv[k+0], p1=poolv[k+1], p2=poolv[k+2], p3=poolv[k+3];
      acc += p0*w0; acc += p1*w1; acc += p2*w2; acc += p3*w3;
    }
  }
  // gf2 -> combT[128..191]
  {
    int cc=t&63, g=t>>6;
    float a = gf2_b[cc];
    #pragma unroll 4
    for(int k=0;k<64;++k) a += hid1s[k*4+g]*gf2_w[k*64+cc];
    combT[(128+cc)*4+g] = a;
  }
  if(half==1) *(v4f*)&partial[c*4] = acc;
  __syncthreads();
  if(half==0){
    v4f pb = *(const v4f*)&partial[c*4];
    float bias = gc_b[c];
    v4f r;
    r.x = fmaxf(acc.x+pb.x+bias, 0.f);
    r.y = fmaxf(acc.y+pb.y+bias, 0.f);
    r.z = fmaxf(acc.z+pb.z+bias, 0.f);
    r.w = fmaxf(acc.w+pb.w+bias, 0.f);
    *(v4f*)&combT[c*4] = r;
  }
  __syncthreads();

  // ---- p1: 192-k split in 2 halves of 96, unroll 4 ----
  v4f a1 = {0.f,0.f,0.f,0.f};
  {
    int kb = half*96;
    for(int kk=0; kk<96; kk+=4){
      int k = kb+kk;
      float w0 = p1_w[(k+0)*128+c];
      float w1 = p1_w[(k+1)*128+c];
      float w2 = p1_w[(k+2)*128+c];
      float w3 = p1_w[(k+3)*128+c];
      v4f p0=combv[k+0], p1=combv[k+1], p2=combv[k+2], p3=combv[k+3];
      a1 += p0*w0; a1 += p1*w1; a1 += p2*w2; a1 += p3*w3;
    }
  }
  if(half==1) *(v4f*)&partial[c*4] = a1;
  __syncthreads();
  if(half==0){
    v4f pb = *(const v4f*)&partial[c*4];
    float b1 = p1_b[c];
    v4f r;
    r.x = fmaxf(a1.x+pb.x+b1, 0.f);
    r.y = fmaxf(a1.y+pb.y+b1, 0.f);
    r.z = fmaxf(a1.z+pb.z+b1, 0.f);
    r.w = fmaxf(a1.w+pb.w+b1, 0.f);
    *(v4f*)&r1T[c*4] = r;
  }
  __syncthreads();

  // ---- p2: 128-k split in 4 quarters of 32, unroll 4 ----
  {
    int c2=t&63, qd=t>>6;
    v4f a2 = {0.f,0.f,0.f,0.f};
    int kb = qd*32;
    for(int kk=0; kk<32; kk+=4){
      int k = kb+kk;
      float w0 = p2_w[(k+0)*64+c2];
      float w1 = p2_w[(k+1)*64+c2];
      float w2 = p2_w[(k+2)*64+c2];
      float w3 = p2_w[(k+3)*64+c2];
      v4f p0=r1v[k+0], p1=r1v[k+1], p2=r1v[k+2], p3=r1v[k+3];
      a2 += p0*w0; a2 += p1*w1; a2 += p2*w2; a2 += p3*w3;
    }
    if(qd>0) *(v4f*)&ppb[((qd-1)*64+c2)*4] = a2;
    __syncthreads();
    if(qd==0){
      v4f q1 = *(const v4f*)&ppb[(0*64+c2)*4];
      v4f q2 = *(const v4f*)&ppb[(1*64+c2)*4];
      v4f q3 = *(const v4f*)&ppb[(2*64+c2)*4];
      float b2 = p2_b[c2];
      v4f r;
      r.x = fmaxf(a2.x+q1.x+q2.x+q3.x+b2, 0.f);
      r.y = fmaxf(a2.y+q1.y+q2.y+q3.y+b2, 0.f);
      r.z = fmaxf(a2.z+q1.z+q2.z+q3.z+b2, 0.f);
      r.w = fmaxf(a2.w+q1.w+q2.w+q3.w+b2, 0.f);
      *(v4f*)&r2T[c2*4] = r;
    }
    __syncthreads();
  }

  // ---- p3 ----
  if(t < 20){
    int g = t/5, o = t%5;
    float a = p3_b[o];
    #pragma unroll 4
    for(int k=0;k<64;++k) a += r2T[k*4+g]*p3_w[k*TOUT+o];
    out[(size_t)(g0+g)*TOUT+o] = a;
  }
}

extern "C" void kernel_launch(void* const* d_in, const int* in_sizes, int n_in,
                              void* d_out, int out_size, void* d_ws, size_t ws_size,
                              hipStream_t stream){
  (void)in_sizes; (void)n_in; (void)out_size; (void)ws_size;
  const float* x        = (const float*)d_in[0];
  const int*   ei       = (const int*)d_in[1];
  const float* ea       = (const float*)d_in[2];
  const int*   batch    = (const int*)d_in[3];
  const float* gfin     = (const float*)d_in[4];
  const float* node_w   = (const float*)d_in[5];
  const float* node_b   = (const float*)d_in[6];
  const float* edge_w   = (const float*)d_in[7];
  const float* edge_b   = (const float*)d_in[8];
  const float* gat_lin_w  = (const float*)d_in[9];
  const float* gat_edge_w = (const float*)d_in[10];
  const float* att_src  = (const float*)d_in[11];
  const float* att_dst  = (const float*)d_in[12];
  const float* att_edge = (const float*)d_in[13];
  const float* gat_bias = (const float*)d_in[14];
  const float* bn_gamma = (const float*)d_in[15];
  const float* bn_beta  = (const float*)d_in[16];
  const float* bn_mean  = (const float*)d_in[17];
  const float* bn_var   = (const float*)d_in[18];
  const float* gc_w = (const float*)d_in[19];
  const float* gc_b = (const float*)d_in[20];
  const float* gf1_w = (const float*)d_in[21];
  const float* gf1_b = (const float*)d_in[22];
  const float* gf2_w = (const float*)d_in[23];
  const float* gf2_b = (const float*)d_in[24];
  const float* p1_w = (const float*)d_in[25];
  const float* p1_b = (const float*)d_in[26];
  const float* p2_w = (const float*)d_in[27];
  const float* p2_b = (const float*)d_in[28];
  const float* p3_w = (const float*)d_in[29];
  const float* p3_b = (const float*)d_in[30];
  float* out = (float*)d_out;

  char* w = (char*)d_ws;
  size_t o = 0;
  auto carve = [&](size_t bytes)->char*{
    char* p = w + o; o += (bytes + 255) & ~(size_t)255; return p;
  };
  unsigned* xhb = (unsigned*)carve((size_t)N_NODES*64*4);
  unsigned* h16 = (unsigned*)carve((size_t)N_NODES*64*4);
  float* ea_csr = (float*)carve((size_t)N_EDGES*4*4);
  float* as_    = (float*)carve((size_t)N_NODES*4*4);
  float* ad_    = (float*)carve((size_t)N_NODES*4*4);
  int* deg      = (int*)carve((size_t)N_NODES*4);
  int* rowptr   = (int*)carve((size_t)(N_NODES+1)*4);
  int* fill     = (int*)carve((size_t)N_NODES*4);
  int* csr_src  = (int*)carve((size_t)N_EDGES*4);
  int* part     = (int*)carve(1024*4);
  float* mebuf  = (float*)carve(64*4);
  float* bnA    = (float*)carve((size_t)NLAYER*HID*4);
  float* bnS    = (float*)carve((size_t)NLAYER*HID*4);
  unsigned short* whi = (unsigned short*)carve(65536*2);
  unsigned short* whiE = (unsigned short*)carve(8192*2);
  unsigned short* wloE = (unsigned short*)carve(8192*2);
  float* pool   = (float*)carve((size_t)N_GRAPHS*384*4);

  // setup: mebuf + BNfold + w_ext + wswz + zero(deg,fill) + hinit
  k_setup<<<1688 + N_NODES/4, 256, 0, stream>>>(gat_edge_w, att_edge, edge_w, edge_b,
        gat_bias, bn_gamma, bn_beta, bn_mean, bn_var,
        gat_lin_w, att_src, att_dst, x, node_w, node_b, h16,
        mebuf, bnA, bnS, whiE, wloE, whi, deg, fill);
  k_deg<<<(N_EDGES+255)/256, 256, 0, stream>>>(ei, deg);
  k_scan1<<<NB,256,0,stream>>>(deg, part);
  k_scan3<<<NB,256,0,stream>>>(deg, part, rowptr);

  for(int l=0;l<NLAYER;++l){
    int gb = (l==0) ? GEMM_BLOCKS + (N_EDGES+255)/256 : GEMM_BLOCKS;
    k_gemm<<<gb,256,0,stream>>>((const unsigned short*)h16,
        whi + l*16384, whiE + l*2048, wloE + l*2048,
        xhb, as_, ad_, ei, ea, rowptr, fill, csr_src, ea_csr);
    k_aggr<<<(N_NODES+7)/8,256,0,stream>>>(xhb, as_, ad_, ea_csr, mebuf,
        rowptr, csr_src, bnA + l*128, bnS + l*128, h16, l);
  }

  k_pool<<<N_GRAPHS,256,0,stream>>>(h16, batch, pool);
  k_head<<<N_GRAPHS/4,256,0,stream>>>(pool, gfin, gc_w, gc_b, gf1_w, gf1_b,
        gf2_w, gf2_b, p1_w, p1_b, p2_w, p2_b, p3_w, p3_b, out);
}